// Round 1
// 419.022 us; speedup vs baseline: 1.0154x; 1.0154x over previous
//
#include <hip/hip_runtime.h>

#define DH 2048               // d_in = d_out = K of GEMM
#define TT 2048
#define BB 4
#define MROWS 8192            // B*T
#define NZ 6144               // GEMM N = 3*DH
#define NCH 128               // scan chunks over T
#define LCH 16                // chunk length
#define LAM 0.44012667f       // 0.95^16
#define LAM2 1.982646e-06f    // 0.95^256

typedef __attribute__((ext_vector_type(8))) short bf16x8;
typedef __attribute__((ext_vector_type(4))) float f32x4;

__device__ __forceinline__ unsigned short f2bf(float f) {
  union { float f; unsigned int u; } v; v.f = f;
  unsigned int u = v.u;
  return (unsigned short)((u + 0x7FFFu + ((u >> 16) & 1u)) >> 16);
}
__device__ __forceinline__ float bf2f(unsigned short u) {
  union { unsigned int i; float f; } v; v.i = ((unsigned int)u) << 16;
  return v.f;
}
__device__ __forceinline__ void gld16(const unsigned short* g, unsigned short* l) {
  __builtin_amdgcn_global_load_lds((const __attribute__((address_space(1))) void*)g,
                                   (__attribute__((address_space(3))) void*)l, 16, 0, 0);
}

// ---- Wt[n][k] = bf16(W[k][o]) with n = mat*2048+o; fused kvWd partials ----
__global__ __launch_bounds__(256) void prep_w(const float* __restrict__ Wp,
                                              const float* __restrict__ Wi,
                                              const float* __restrict__ Wd,
                                              const float* __restrict__ kick_vec,
                                              unsigned short* __restrict__ Wt,
                                              float* __restrict__ kvWd) {
  __shared__ float tile[64][65];
  int bid = blockIdx.x;                 // 3 * 32 * 32 = 3072
  int mat = bid >> 10;
  int t2 = bid & 1023;
  int dt = (t2 >> 5) * 64;
  int ot = (t2 & 31) * 64;
  const float* W = (mat == 0) ? Wp : ((mat == 1) ? Wi : Wd);
  int nbase = mat * DH;
  int tid = threadIdx.x;
  int r = tid >> 4;
  int c4 = (tid & 15) * 4;
#pragma unroll
  for (int i = 0; i < 4; ++i) {
    int rr = r + i * 16;
    float4 v = *(const float4*)&W[(size_t)(dt + rr) * DH + ot + c4];
    tile[rr][c4 + 0] = v.x; tile[rr][c4 + 1] = v.y;
    tile[rr][c4 + 2] = v.z; tile[rr][c4 + 3] = v.w;
  }
  __syncthreads();
  int o = tid >> 3;                     // 0..31
  int d8 = (tid & 7) * 8;
#pragma unroll
  for (int pass = 0; pass < 2; ++pass) {
    int oo = o + pass * 32;
    union { unsigned short u[8]; uint4 v; } pk;
#pragma unroll
    for (int i = 0; i < 8; ++i) pk.u[i] = f2bf(tile[d8 + i][oo]);
    *(uint4*)&Wt[(size_t)(nbase + ot + oo) * DH + dt + d8] = pk.v;
  }
  if (mat == 2 && tid < 64) {
    float s = 0.f;
#pragma unroll 8
    for (int dd = 0; dd < 64; ++dd) s += kick_vec[dt + dd] * tile[dd][tid];
    atomicAdd(&kvWd[ot + tid], s);
  }
}

// ---- fused rowstats + bf16(x) conversion (A staged in d_out) ----
__global__ __launch_bounds__(256) void conv_x(const float* __restrict__ x,
                                              const float* __restrict__ gate_w,
                                              const float* __restrict__ gate_b,
                                              const float* __restrict__ kick_w,
                                              const float* __restrict__ kick_b,
                                              float* __restrict__ rs,
                                              unsigned short* __restrict__ A) {
  int r = blockIdx.x;                   // 8192
  int t = r & (TT - 1);
  const float* xr = x + (size_t)r * DH;
  const float* xq = xr - DH;
  const bool hp = (t != 0);
  int tid = threadIdx.x;
  float a0 = 0, a1 = 0, a2 = 0, ak = 0, axx = 0, apx = 0, app = 0;
#pragma unroll
  for (int it = 0; it < 2; ++it) {
    int d0 = (tid + it * 256) * 4;
    float4 xv = *(const float4*)(xr + d0);
    float4 pv = hp ? *(const float4*)(xq + d0) : make_float4(0.f, 0.f, 0.f, 0.f);
    float4 q0 = *(const float4*)(gate_w + (size_t)d0 * 3);
    float4 q1 = *(const float4*)(gate_w + (size_t)d0 * 3 + 4);
    float4 q2 = *(const float4*)(gate_w + (size_t)d0 * 3 + 8);
    float4 kw = *(const float4*)(kick_w + d0);
    float xa[4] = {xv.x, xv.y, xv.z, xv.w};
    float pa[4] = {pv.x, pv.y, pv.z, pv.w};
    a0 += xa[0] * q0.x + xa[1] * q0.w + xa[2] * q1.z + xa[3] * q2.y;
    a1 += xa[0] * q0.y + xa[1] * q1.x + xa[2] * q1.w + xa[3] * q2.z;
    a2 += xa[0] * q0.z + xa[1] * q1.y + xa[2] * q2.x + xa[3] * q2.w;
    ak += xa[0] * kw.x + xa[1] * kw.y + xa[2] * kw.z + xa[3] * kw.w;
    union { unsigned short u[4]; uint2 v; } pk;
#pragma unroll
    for (int j = 0; j < 4; ++j) {
      axx += xa[j] * xa[j];
      apx += xa[j] * pa[j];
      app += pa[j] * pa[j];
      pk.u[j] = f2bf(xa[j]);
    }
    *(uint2*)&A[(size_t)r * DH + d0] = pk.v;
  }
#pragma unroll
  for (int off = 32; off > 0; off >>= 1) {
    a0 += __shfl_xor(a0, off); a1 += __shfl_xor(a1, off);
    a2 += __shfl_xor(a2, off); ak += __shfl_xor(ak, off);
    axx += __shfl_xor(axx, off); apx += __shfl_xor(apx, off);
    app += __shfl_xor(app, off);
  }
  __shared__ float red[4][7];
  int wv = tid >> 6;
  if ((tid & 63) == 0) {
    red[wv][0] = a0; red[wv][1] = a1; red[wv][2] = a2; red[wv][3] = ak;
    red[wv][4] = axx; red[wv][5] = apx; red[wv][6] = app;
  }
  __syncthreads();
  if (tid == 0) {
    float v[7];
#pragma unroll
    for (int i = 0; i < 7; ++i) v[i] = red[0][i] + red[1][i] + red[2][i] + red[3][i];
    float l0 = v[0] + gate_b[0], l1 = v[1] + gate_b[1], l2 = v[2] + gate_b[2];
    float mx = fmaxf(l0, fmaxf(l1, l2));
    float e0 = expf(l0 - mx), e1 = expf(l1 - mx), e2 = expf(l2 - mx);
    float inv = 1.f / (e0 + e1 + e2);
    float G0 = fminf(e0 * inv, 0.6f);
    float G1 = fminf(e1 * inv, 0.6f);
    float G2 = fminf(e2 * inv, 0.6f);
    G1 = fmaxf(G1, 0.25f);
    float inv2 = 1.f / (G0 + G1 + G2);
    G0 *= inv2; G1 *= inv2; G2 *= inv2;
    float ks = 1.f / (1.f + expf(-(v[3] + kick_b[0])));
    float nn = fmaxf(sqrtf(v[4]), 1e-12f) * fmaxf(sqrtf(v[6]), 1e-12f);
    float cs = hp ? (v[5] / nn) : 0.f;
    float cc = (cs > 0.95f) ? (G2 * ks) : 0.f;
    *(float4*)(rs + (size_t)r * 4) = make_float4(G0, G1, G2, cc);
  }
}

// ---- GEMM: 256x256 tile, BK=64, 8 waves, 8-phase counted-vmcnt schedule ----
// Z(8192x6144, bf16) = A(8192x2048) @ Wt^T; fused Zi chunk-carry (cpb).
// Schedule (per iteration = K-tiles T=2i in buf0, T+1 in buf1):
//  P1: rdA(h0)+rdB(g0) | stage (T+1).B1  vm8   P5: rdA/rdB buf1 | stage (T+2).B1  vm8
//  P2: rdB(g1)         | stage (T+1).A1  vm8   P6: rdB(g1)      | stage (T+2).A1  vm8
//  P3: rdA(h1)         | stage (T+2).A0   -    P7: rdA(h1)      | stage (T+3).A0   -
//  P4:  -              | stage (T+2).B0  vm8   P8:  -           | stage (T+3).B0  vm8
// Each phase: [ds_read][2x gld_lds][vmcnt][s_barrier][lgkmcnt(0)][setprio1][16 MFMA][setprio0][s_barrier]
// vmcnt(8) leaves 4 half-tiles in flight; every read verified covered by a prior wait+barrier.

#define BAR __builtin_amdgcn_s_barrier()
#define VMW8 asm volatile("s_waitcnt vmcnt(8)" ::: "memory")
#define VMW4 asm volatile("s_waitcnt vmcnt(4)" ::: "memory")
#define VMW2 asm volatile("s_waitcnt vmcnt(2)" ::: "memory")
#define VMW0 asm volatile("s_waitcnt vmcnt(0)" ::: "memory")
#define LGK0 asm volatile("s_waitcnt lgkmcnt(0)" ::: "memory")

#define ST_A(bf, h, kt) do { \
  gld16(pA + (size_t)((h) * 64) * DH + (kt) * 64,       lA + (bf) * 16384 + (h) * 8192 + ldsW); \
  gld16(pA + (size_t)((h) * 64 + 128) * DH + (kt) * 64, lA + (bf) * 16384 + (h) * 8192 + 4096 + ldsW); \
} while (0)
#define ST_B(bf, g, kt) do { \
  gld16(pB + (size_t)((g) * 32) * DH + (kt) * 64,       lB + (bf) * 16384 + (g) * 8192 + ldsW); \
  gld16(pB + (size_t)((g) * 32 + 128) * DH + (kt) * 64, lB + (bf) * 16384 + (g) * 8192 + 4096 + ldsW); \
} while (0)

#define RD_A(bf, h) do { \
  const unsigned short* p_ = lA + (bf) * 16384 + (h) * 8192 + aRd; \
  _Pragma("unroll") \
  for (int mi_ = 0; mi_ < 4; ++mi_) { \
    av[mi_][0] = *(const bf16x8*)(p_ + mi_ * 1024 + kph0); \
    av[mi_][1] = *(const bf16x8*)(p_ + mi_ * 1024 + kph1); \
  } \
} while (0)
#define RD_B(bf, g) do { \
  const unsigned short* p_ = lB + (bf) * 16384 + (g) * 8192 + bRd; \
  _Pragma("unroll") \
  for (int ni_ = 0; ni_ < 2; ++ni_) { \
    bv[g][ni_][0] = *(const bf16x8*)(p_ + ni_ * 1024 + kph0); \
    bv[g][ni_][1] = *(const bf16x8*)(p_ + ni_ * 1024 + kph1); \
  } \
} while (0)

#define MM(h, g) do { \
  __builtin_amdgcn_s_setprio(1); \
  _Pragma("unroll") \
  for (int mi_ = 0; mi_ < 4; ++mi_) { \
    _Pragma("unroll") \
    for (int ni_ = 0; ni_ < 2; ++ni_) { \
      f32x4 c_ = acc[(h) * 4 + mi_][(g) * 2 + ni_]; \
      c_ = __builtin_amdgcn_mfma_f32_16x16x32_bf16(av[mi_][0], bv[g][ni_][0], c_, 0, 0, 0); \
      c_ = __builtin_amdgcn_mfma_f32_16x16x32_bf16(av[mi_][1], bv[g][ni_][1], c_, 0, 0, 0); \
      acc[(h) * 4 + mi_][(g) * 2 + ni_] = c_; \
    } \
  } \
  __builtin_amdgcn_s_setprio(0); \
} while (0)

__global__ __launch_bounds__(512, 2) void gemm_kernel(const unsigned short* __restrict__ A,
                                                      const unsigned short* __restrict__ Bt,
                                                      unsigned short* __restrict__ Z,
                                                      unsigned short* __restrict__ cpb) {
  // LDS: [buf][half][part][64][64] for A (part = wm), [buf][half][wn][32][64] for B. 128 KiB.
  __shared__ __align__(16) unsigned short lA[2 * 16384];
  __shared__ __align__(16) unsigned short lB[2 * 16384];
  const int tid = threadIdx.x;          // 0..511
  const int wave = tid >> 6, lane = tid & 63;
  const int bid = blockIdx.x;           // 768 = 32 mblk * 24 nblk
  const int xcd = bid & 7;
  const int loc = bid >> 3;             // 0..95
  const int mblk = xcd * 4 + (loc & 3); // 0..31
  const int nblk = loc >> 2;            // 0..23
  const int m0 = mblk * 256, n0 = nblk * 256;

  const int wm = wave >> 2, wn = wave & 3;      // wave tile: 128(M) x 64(N)
  const int rA = lane & 15, q = lane >> 4, sw = lane & 7;
  const int kph0 = ((0 + q) ^ sw) * 8;          // swizzled k-slot, kb=0
  const int kph1 = ((4 + q) ^ sw) * 8;          // kb=1
  const int aRd = wm * 4096 + rA * 64;
  const int bRd = wn * 2048 + rA * 64;

  // staging: thread t covers row trow (of a 64-row part), 16B slot (t&7), src pre-swizzled
  const int trow = tid >> 3;            // 0..63
  const int tcol = ((tid & 7) ^ (trow & 7)) * 8;
  const unsigned short* pA = A + (size_t)(m0 + trow) * DH + tcol;
  const unsigned short* pB = Bt + (size_t)(n0 + (trow >> 5) * 64 + (trow & 31)) * DH + tcol;
  const int ldsW = wave * 512;          // lane-linear LDS dest base (elements)

  bf16x8 av[4][2];                      // A frags: current m-half, 4 mi x 2 kb
  bf16x8 bv[2][2][2];                   // B frags: both n-halves x 2 ni x 2 kb
  f32x4 acc[8][4] = {};

  // prologue: T0.{A0,B0,B1,A1}, T1.{A0,B0} (12 loads); retire T0.A0,B0
  ST_A(0, 0, 0); ST_B(0, 0, 0); ST_B(0, 1, 0); ST_A(0, 1, 0);
  ST_A(1, 0, 1); ST_B(1, 0, 1);
  VMW8; BAR;

#pragma unroll 1
  for (int i = 0; i < 15; ++i) {
    const int t1 = 2 * i + 1, t2 = 2 * i + 2, t3 = 2 * i + 3;
    // ---- K-tile 2i in buf0 ----
    RD_A(0, 0); RD_B(0, 0); ST_B(1, 1, t1); VMW8; BAR; LGK0; MM(0, 0); BAR;  // P1
    RD_B(0, 1);             ST_A(1, 1, t1); VMW8; BAR; LGK0; MM(0, 1); BAR;  // P2
    RD_A(0, 1);             ST_A(0, 0, t2);       BAR; LGK0; MM(1, 0); BAR;  // P3
                            ST_B(0, 0, t2); VMW8; BAR; LGK0; MM(1, 1); BAR;  // P4
    // ---- K-tile 2i+1 in buf1 ----
    RD_A(1, 0); RD_B(1, 0); ST_B(0, 1, t2); VMW8; BAR; LGK0; MM(0, 0); BAR;  // P5
    RD_B(1, 1);             ST_A(0, 1, t2); VMW8; BAR; LGK0; MM(0, 1); BAR;  // P6
    RD_A(1, 1);             ST_A(1, 0, t3);       BAR; LGK0; MM(1, 0); BAR;  // P7
                            ST_B(1, 0, t3); VMW8; BAR; LGK0; MM(1, 1); BAR;  // P8
  }
  // peeled last iteration (tiles 30, 31): drain 8 -> 8 -> 4 -> 2 -> 0
  RD_A(0, 0); RD_B(0, 0); ST_B(1, 1, 31); VMW8; BAR; LGK0; MM(0, 0); BAR;
  RD_B(0, 1);             ST_A(1, 1, 31); VMW8; BAR; LGK0; MM(0, 1); BAR;
  RD_A(0, 1);                                   BAR; LGK0; MM(1, 0); BAR;
                                          VMW4; BAR; LGK0; MM(1, 1); BAR;
  RD_A(1, 0); RD_B(1, 0);                 VMW2; BAR; LGK0; MM(0, 0); BAR;
  RD_B(1, 1);                             VMW0; BAR; LGK0; MM(0, 1); BAR;
  RD_A(1, 1);                                   BAR; LGK0; MM(1, 0); BAR;
                                                            MM(1, 1);

  const int mbase = m0 + wm * 128;
  const int nbase = n0 + wn * 64;

  // fused Zi chunk-local EMA carry: chunk == one mi block (16 rows).
  if (nblk >= 8 && nblk < 16) {
    float w12 = (q == 3) ? 1.0f : (q == 2) ? 0.81450625f
              : (q == 1) ? 0.66342043f : 0.54036009f;   // 0.95^(12-4*q)
    w12 *= 0.05f;
#pragma unroll
    for (int mi = 0; mi < 8; ++mi) {
      const int mrow = mbase + mi * 16;
      const int bb = mrow >> 11;
      const int chh = (mrow >> 4) & (NCH - 1);
      const bool first = (chh == 0);
#pragma unroll
      for (int ni = 0; ni < 4; ++ni) {
        float v0 = acc[mi][ni][0];
        float s = ((v0 * 0.95f + acc[mi][ni][1]) * 0.95f + acc[mi][ni][2]) * 0.95f
                  + acc[mi][ni][3];
        if (first && q == 0) s += 19.0f * 0.857375f * v0;  // row0 coef -> 0.95^15
        s *= w12;
        s += __shfl_xor(s, 16);
        s += __shfl_xor(s, 32);
        if (q == 0) {
          int nloc = nbase + ni * 16 + rA - 2048;
          cpb[((size_t)bb * NCH + chh) * DH + nloc] = f2bf(s);
        }
      }
    }
  }

#pragma unroll
  for (int ni = 0; ni < 4; ++ni) {
    const int n = nbase + ni * 16 + rA;
#pragma unroll
    for (int mi = 0; mi < 8; ++mi) {
#pragma unroll
      for (int rg = 0; rg < 4; ++rg) {
        const int m = mbase + mi * 16 + q * 4 + rg;
        Z[(size_t)m * NZ + n] = f2bf(acc[mi][ni][rg]);
      }
    }
  }
}

#undef BAR
#undef VMW8
#undef VMW4
#undef VMW2
#undef VMW0
#undef LGK0
#undef ST_A
#undef ST_B
#undef RD_A
#undef RD_B
#undef MM

// ---- prefix level 1: within-group (16 chunks) relative prefix + group totals ----
__global__ __launch_bounds__(256) void zi_p1(unsigned short* __restrict__ cpb,
                                             float* __restrict__ gc) {
  int gid = blockIdx.x * 256 + threadIdx.x;   // (b, g, n): 4*8*2048 = 65536
  int n = gid & (DH - 1);
  int g = (gid >> 11) & 7;
  int b = gid >> 14;
  float run = 0.f;
#pragma unroll
  for (int j = 0; j < 16; ++j) {
    size_t idx = ((size_t)b * NCH + g * 16 + j) * DH + n;
    float c = bf2f(cpb[idx]);
    cpb[idx] = f2bf(run);
    run = c + LAM * run;
  }
  gc[((size_t)b * 8 + g) * DH + n] = run;
}

// ---- prefix level 2: scan group totals in place -> carry INTO each group ----
__global__ __launch_bounds__(256) void zi_p2(float* __restrict__ gc) {
  int gid = blockIdx.x * 256 + threadIdx.x;   // (b, n): 8192
  int n = gid & (DH - 1);
  int b = gid >> 11;
  float run = 0.f;
#pragma unroll
  for (int g = 0; g < 8; ++g) {
    size_t idx = ((size_t)b * 8 + g) * DH + n;
    float old = gc[idx];
    gc[idx] = run;
    run = old + LAM2 * run;
  }
}

// ---- final: out = g0*Zp + g1*EMA(Zi) + g2*(Zd - Zd_prev) + cc*kvWd + bias ----
__global__ __launch_bounds__(256) void final_combine(const unsigned short* __restrict__ Z,
                                                     const float* __restrict__ rs,
                                                     const unsigned short* __restrict__ cpb,
                                                     const float* __restrict__ gc,
                                                     const float* __restrict__ kvWd,
                                                     const float* __restrict__ bias,
                                                     float* __restrict__ out) {
  int tid = threadIdx.x;
  int n = blockIdx.y * 1024 + tid * 4;  // 4 cols/thread
  int ch = blockIdx.x & (NCH - 1);      // grid (512, 2)
  int b = blockIdx.x >> 7;
  int r0 = b * TT + ch * LCH;
  const unsigned short* zb = Z + (size_t)r0 * NZ + n;
  const bool first_chunk = (ch == 0);

  int g = ch >> 4, j = ch & 15;
  float pw = 1.f;
  for (int i = 0; i < j; ++i) pw *= LAM;
  float Pv[4];
  {
    union { unsigned short u[4]; uint2 v; } c;
    c.v = *(const uint2*)&cpb[((size_t)b * NCH + ch) * DH + n];
    float4 gp = *(const float4*)&gc[((size_t)b * 8 + g) * DH + n];
    float gpa[4] = {gp.x, gp.y, gp.z, gp.w};
#pragma unroll
    for (int i = 0; i < 4; ++i) Pv[i] = bf2f(c.u[i]) + pw * gpa[i];
  }
  float kv[4], bz[4];
  {
    float4 k0 = *(const float4*)&kvWd[n];
    float4 b0 = *(const float4*)&bias[n];
    kv[0]=k0.x; kv[1]=k0.y; kv[2]=k0.z; kv[3]=k0.w;
    bz[0]=b0.x; bz[1]=b0.y; bz[2]=b0.z; bz[3]=b0.w;
  }
  float zdp[4];
  if (!first_chunk) {
    union { unsigned short u[4]; uint2 v; } c;
    c.v = *(const uint2*)(zb - NZ + 2 * DH);
#pragma unroll
    for (int i = 0; i < 4; ++i) zdp[i] = bf2f(c.u[i]);
  } else {
#pragma unroll
    for (int i = 0; i < 4; ++i) zdp[i] = 0.f;
  }
  float J[4];
#pragma unroll
  for (int i = 0; i < 4; ++i) J[i] = 0.f;
  float f = 1.f;
  uint2 cp = *(const uint2*)(zb);
  uint2 ci = *(const uint2*)(zb + DH);
  uint2 cd = *(const uint2*)(zb + 2 * DH);
#pragma unroll
  for (int tau = 0; tau < LCH; ++tau) {
    uint2 np, ni, nd;
    if (tau < LCH - 1) {
      const unsigned short* zn = zb + (size_t)(tau + 1) * NZ;
      np = *(const uint2*)(zn);
      ni = *(const uint2*)(zn + DH);
      nd = *(const uint2*)(zn + 2 * DH);
    }
    float4 gg = *(const float4*)&rs[(size_t)(r0 + tau) * 4];
    union { unsigned short u[4]; uint2 v; } up, ui, ud;
    up.v = cp; ui.v = ci; ud.v = cd;
    const bool vfirst = first_chunk && (tau == 0);
    f *= 0.95f;
    float o[4];
#pragma unroll
    for (int i = 0; i < 4; ++i) {
      float xp = bf2f(up.u[i]), xi = bf2f(ui.u[i]), xd = bf2f(ud.u[i]);
      if (vfirst) J[i] = xi;
      else J[i] = 0.95f * J[i] + 0.05f * xi;
      float I = J[i] + f * Pv[i];
      float diff = vfirst ? 0.f : (xd - zdp[i]);
      o[i] = gg.x * xp + gg.y * I + gg.z * diff + gg.w * kv[i] + bz[i];
      zdp[i] = xd;
    }
    *(float4*)(out + (size_t)(r0 + tau) * DH + n) = make_float4(o[0], o[1], o[2], o[3]);
    cp = np; ci = ni; cd = nd;
  }
}

extern "C" void kernel_launch(void* const* d_in, const int* in_sizes, int n_in,
                              void* d_out, int out_size, void* d_ws, size_t ws_size,
                              hipStream_t stream) {
  const float* x        = (const float*)d_in[0];
  const float* Wp       = (const float*)d_in[1];
  const float* Wi       = (const float*)d_in[2];
  const float* Wd       = (const float*)d_in[3];
  const float* gate_w   = (const float*)d_in[4];
  const float* gate_b   = (const float*)d_in[5];
  const float* kick_vec = (const float*)d_in[6];
  const float* kick_w   = (const float*)d_in[7];
  const float* kick_b   = (const float*)d_in[8];
  const float* bias     = (const float*)d_in[9];
  float* out = (float*)d_out;

  char* ws = (char*)d_ws;
  // workspace layout (bytes), total 128,327,680 (< proven 130,293,760)
  unsigned short* Wt  = (unsigned short*)(ws + 0);           // 6144*2048*2  = 25,165,824
  unsigned short* Z   = (unsigned short*)(ws + 25165824);    // 8192*6144*2  = 100,663,296
  float* rs   = (float*)(ws + 125829120);                    // 8192*4*4     = 131,072
  float* kvWd = (float*)(ws + 125960192);                    // 2048*4       = 8,192
  unsigned short* cpb = (unsigned short*)(ws + 125968384);   // 4*128*2048*2 = 2,097,152
  float* gc   = (float*)(ws + 128065536);                    // 4*8*2048*4   = 262,144
  // A (bf16 x) staged in d_out: 8192*2048*2 = 33,554,432 <= 67 MB; dead before final writes
  unsigned short* A = (unsigned short*)d_out;
  (void)ws_size; (void)in_sizes; (void)n_in; (void)out_size;

  hipMemsetAsync(kvWd, 0, DH * sizeof(float), stream);
  prep_w<<<dim3(3072), dim3(256), 0, stream>>>(Wp, Wi, Wd, kick_vec, Wt, kvWd);
  conv_x<<<dim3(8192), dim3(256), 0, stream>>>(x, gate_w, gate_b, kick_w, kick_b, rs, A);
  gemm_kernel<<<dim3(768), dim3(512), 0, stream>>>(A, Wt, Z, cpb);
  zi_p1<<<dim3(256), dim3(256), 0, stream>>>(cpb, gc);
  zi_p2<<<dim3(32), dim3(256), 0, stream>>>(gc);
  final_combine<<<dim3(512, 2), dim3(256), 0, stream>>>(Z, rs, cpb, gc, kvWd, bias, out);
}

// Round 3
// 390.240 us; speedup vs baseline: 1.0903x; 1.0738x over previous
//
#include <hip/hip_runtime.h>

#define DH 2048               // d_in = d_out = K of GEMM
#define TT 2048
#define BB 4
#define MROWS 8192            // B*T
#define NZ 6144               // GEMM N = 3*DH
#define NCH 128               // scan chunks over T
#define LCH 16                // chunk length
#define LAM 0.44012667f       // 0.95^16
#define LAM2 1.982646e-06f    // 0.95^256

typedef __attribute__((ext_vector_type(8))) short bf16x8;
typedef __attribute__((ext_vector_type(4))) float f32x4;

__device__ __forceinline__ unsigned short f2bf(float f) {
  union { float f; unsigned int u; } v; v.f = f;
  unsigned int u = v.u;
  return (unsigned short)((u + 0x7FFFu + ((u >> 16) & 1u)) >> 16);
}
__device__ __forceinline__ float bf2f(unsigned short u) {
  union { unsigned int i; float f; } v; v.i = ((unsigned int)u) << 16;
  return v.f;
}
__device__ __forceinline__ void gld16(const unsigned short* g, unsigned short* l) {
  __builtin_amdgcn_global_load_lds((const __attribute__((address_space(1))) void*)g,
                                   (__attribute__((address_space(3))) void*)l, 16, 0, 0);
}

// ---- Wt[n][k] = bf16(W[k][o]) with n = mat*2048+o; fused kvWd partials ----
__global__ __launch_bounds__(256) void prep_w(const float* __restrict__ Wp,
                                              const float* __restrict__ Wi,
                                              const float* __restrict__ Wd,
                                              const float* __restrict__ kick_vec,
                                              unsigned short* __restrict__ Wt,
                                              float* __restrict__ kvWd) {
  __shared__ float tile[64][65];
  int bid = blockIdx.x;                 // 3 * 32 * 32 = 3072
  int mat = bid >> 10;
  int t2 = bid & 1023;
  int dt = (t2 >> 5) * 64;
  int ot = (t2 & 31) * 64;
  const float* W = (mat == 0) ? Wp : ((mat == 1) ? Wi : Wd);
  int nbase = mat * DH;
  int tid = threadIdx.x;
  int r = tid >> 4;
  int c4 = (tid & 15) * 4;
#pragma unroll
  for (int i = 0; i < 4; ++i) {
    int rr = r + i * 16;
    float4 v = *(const float4*)&W[(size_t)(dt + rr) * DH + ot + c4];
    tile[rr][c4 + 0] = v.x; tile[rr][c4 + 1] = v.y;
    tile[rr][c4 + 2] = v.z; tile[rr][c4 + 3] = v.w;
  }
  __syncthreads();
  int o = tid >> 3;                     // 0..31
  int d8 = (tid & 7) * 8;
#pragma unroll
  for (int pass = 0; pass < 2; ++pass) {
    int oo = o + pass * 32;
    union { unsigned short u[8]; uint4 v; } pk;
#pragma unroll
    for (int i = 0; i < 8; ++i) pk.u[i] = f2bf(tile[d8 + i][oo]);
    *(uint4*)&Wt[(size_t)(nbase + ot + oo) * DH + dt + d8] = pk.v;
  }
  if (mat == 2 && tid < 64) {
    float s = 0.f;
#pragma unroll 8
    for (int dd = 0; dd < 64; ++dd) s += kick_vec[dt + dd] * tile[dd][tid];
    atomicAdd(&kvWd[ot + tid], s);
  }
}

// ---- fused rowstats + bf16(x) conversion (A staged in d_out) ----
__global__ __launch_bounds__(256) void conv_x(const float* __restrict__ x,
                                              const float* __restrict__ gate_w,
                                              const float* __restrict__ gate_b,
                                              const float* __restrict__ kick_w,
                                              const float* __restrict__ kick_b,
                                              float* __restrict__ rs,
                                              unsigned short* __restrict__ A) {
  int r = blockIdx.x;                   // 8192
  int t = r & (TT - 1);
  const float* xr = x + (size_t)r * DH;
  const float* xq = xr - DH;
  const bool hp = (t != 0);
  int tid = threadIdx.x;
  float a0 = 0, a1 = 0, a2 = 0, ak = 0, axx = 0, apx = 0, app = 0;
#pragma unroll
  for (int it = 0; it < 2; ++it) {
    int d0 = (tid + it * 256) * 4;
    float4 xv = *(const float4*)(xr + d0);
    float4 pv = hp ? *(const float4*)(xq + d0) : make_float4(0.f, 0.f, 0.f, 0.f);
    float4 q0 = *(const float4*)(gate_w + (size_t)d0 * 3);
    float4 q1 = *(const float4*)(gate_w + (size_t)d0 * 3 + 4);
    float4 q2 = *(const float4*)(gate_w + (size_t)d0 * 3 + 8);
    float4 kw = *(const float4*)(kick_w + d0);
    float xa[4] = {xv.x, xv.y, xv.z, xv.w};
    float pa[4] = {pv.x, pv.y, pv.z, pv.w};
    a0 += xa[0] * q0.x + xa[1] * q0.w + xa[2] * q1.z + xa[3] * q2.y;
    a1 += xa[0] * q0.y + xa[1] * q1.x + xa[2] * q1.w + xa[3] * q2.z;
    a2 += xa[0] * q0.z + xa[1] * q1.y + xa[2] * q2.x + xa[3] * q2.w;
    ak += xa[0] * kw.x + xa[1] * kw.y + xa[2] * kw.z + xa[3] * kw.w;
    union { unsigned short u[4]; uint2 v; } pk;
#pragma unroll
    for (int j = 0; j < 4; ++j) {
      axx += xa[j] * xa[j];
      apx += xa[j] * pa[j];
      app += pa[j] * pa[j];
      pk.u[j] = f2bf(xa[j]);
    }
    *(uint2*)&A[(size_t)r * DH + d0] = pk.v;
  }
#pragma unroll
  for (int off = 32; off > 0; off >>= 1) {
    a0 += __shfl_xor(a0, off); a1 += __shfl_xor(a1, off);
    a2 += __shfl_xor(a2, off); ak += __shfl_xor(ak, off);
    axx += __shfl_xor(axx, off); apx += __shfl_xor(apx, off);
    app += __shfl_xor(app, off);
  }
  __shared__ float red[4][7];
  int wv = tid >> 6;
  if ((tid & 63) == 0) {
    red[wv][0] = a0; red[wv][1] = a1; red[wv][2] = a2; red[wv][3] = ak;
    red[wv][4] = axx; red[wv][5] = apx; red[wv][6] = app;
  }
  __syncthreads();
  if (tid == 0) {
    float v[7];
#pragma unroll
    for (int i = 0; i < 7; ++i) v[i] = red[0][i] + red[1][i] + red[2][i] + red[3][i];
    float l0 = v[0] + gate_b[0], l1 = v[1] + gate_b[1], l2 = v[2] + gate_b[2];
    float mx = fmaxf(l0, fmaxf(l1, l2));
    float e0 = expf(l0 - mx), e1 = expf(l1 - mx), e2 = expf(l2 - mx);
    float inv = 1.f / (e0 + e1 + e2);
    float G0 = fminf(e0 * inv, 0.6f);
    float G1 = fminf(e1 * inv, 0.6f);
    float G2 = fminf(e2 * inv, 0.6f);
    G1 = fmaxf(G1, 0.25f);
    float inv2 = 1.f / (G0 + G1 + G2);
    G0 *= inv2; G1 *= inv2; G2 *= inv2;
    float ks = 1.f / (1.f + expf(-(v[3] + kick_b[0])));
    float nn = fmaxf(sqrtf(v[4]), 1e-12f) * fmaxf(sqrtf(v[6]), 1e-12f);
    float cs = hp ? (v[5] / nn) : 0.f;
    float cc = (cs > 0.95f) ? (G2 * ks) : 0.f;
    *(float4*)(rs + (size_t)r * 4) = make_float4(G0, G1, G2, cc);
  }
}

// ---- GEMM: 256x256 tile, BK=64, 8 waves, 8-phase rotated-stage schedule ----
// WAR-safe rotation: each phase stages only a region whose read completed in a
// STRICTLY EARLIER phase (barrier-separated). Waits ONLY at P4/P8, vmcnt(6).
// At each wait: 14 loads outstanding, vmcnt(6) retires the oldest 8 = one buffer.

#define BAR __builtin_amdgcn_s_barrier()
#define VMW6 asm volatile("s_waitcnt vmcnt(6)" ::: "memory")
#define VMW0 asm volatile("s_waitcnt vmcnt(0)" ::: "memory")
#define LGK8 asm volatile("s_waitcnt lgkmcnt(8)" ::: "memory")
#define LGK0 asm volatile("s_waitcnt lgkmcnt(0)" ::: "memory")

#define ST_A(bf, h, kt) do { \
  gld16(pA + (size_t)((h) * 64) * DH + (kt) * 64,       lA + (bf) * 16384 + (h) * 8192 + ldsW); \
  gld16(pA + (size_t)((h) * 64 + 128) * DH + (kt) * 64, lA + (bf) * 16384 + (h) * 8192 + 4096 + ldsW); \
} while (0)
#define ST_B(bf, g, kt) do { \
  gld16(pB + (size_t)((g) * 32) * DH + (kt) * 64,       lB + (bf) * 16384 + (g) * 8192 + ldsW); \
  gld16(pB + (size_t)((g) * 32 + 128) * DH + (kt) * 64, lB + (bf) * 16384 + (g) * 8192 + 4096 + ldsW); \
} while (0)

#define RD_A(bf, h) do { \
  const unsigned short* p_ = lA + (bf) * 16384 + (h) * 8192 + aRd; \
  _Pragma("unroll") \
  for (int mi_ = 0; mi_ < 4; ++mi_) { \
    av[mi_][0] = *(const bf16x8*)(p_ + mi_ * 1024 + kph0); \
    av[mi_][1] = *(const bf16x8*)(p_ + mi_ * 1024 + kph1); \
  } \
} while (0)
#define RD_B(bf, g) do { \
  const unsigned short* p_ = lB + (bf) * 16384 + (g) * 8192 + bRd; \
  _Pragma("unroll") \
  for (int ni_ = 0; ni_ < 2; ++ni_) { \
    bv[g][ni_][0] = *(const bf16x8*)(p_ + ni_ * 1024 + kph0); \
    bv[g][ni_][1] = *(const bf16x8*)(p_ + ni_ * 1024 + kph1); \
  } \
} while (0)

#define MM(h, g) do { \
  __builtin_amdgcn_s_setprio(1); \
  _Pragma("unroll") \
  for (int mi_ = 0; mi_ < 4; ++mi_) { \
    _Pragma("unroll") \
    for (int ni_ = 0; ni_ < 2; ++ni_) { \
      f32x4 c_ = acc[(h) * 4 + mi_][(g) * 2 + ni_]; \
      c_ = __builtin_amdgcn_mfma_f32_16x16x32_bf16(av[mi_][0], bv[g][ni_][0], c_, 0, 0, 0); \
      c_ = __builtin_amdgcn_mfma_f32_16x16x32_bf16(av[mi_][1], bv[g][ni_][1], c_, 0, 0, 0); \
      acc[(h) * 4 + mi_][(g) * 2 + ni_] = c_; \
    } \
  } \
  __builtin_amdgcn_s_setprio(0); \
} while (0)

__global__ __launch_bounds__(512, 2) void gemm_kernel(const unsigned short* __restrict__ A,
                                                      const unsigned short* __restrict__ Bt,
                                                      unsigned short* __restrict__ Z,
                                                      unsigned short* __restrict__ cpb) {
  __shared__ __align__(16) unsigned short lA[2 * 16384];
  __shared__ __align__(16) unsigned short lB[2 * 16384];
  const int tid = threadIdx.x;          // 0..511
  const int wave = tid >> 6, lane = tid & 63;
  const int bid = blockIdx.x;           // 768 = 32 mblk * 24 nblk
  const int xcd = bid & 7;
  const int loc = bid >> 3;             // 0..95
  const int mblk = xcd * 4 + (loc & 3); // 0..31
  const int nblk = loc >> 2;            // 0..23
  const int m0 = mblk * 256, n0 = nblk * 256;

  const int wm = wave >> 2, wn = wave & 3;      // wave tile: 128(M) x 64(N)
  const int rA = lane & 15, q = lane >> 4, sw = lane & 7;
  const int kph0 = ((0 + q) ^ sw) * 8;          // swizzled k-slot, kb=0
  const int kph1 = ((4 + q) ^ sw) * 8;          // kb=1
  const int aRd = wm * 4096 + rA * 64;
  const int bRd = wn * 2048 + rA * 64;

  const int trow = tid >> 3;            // 0..63
  const int tcol = ((tid & 7) ^ (trow & 7)) * 8;
  const unsigned short* pA = A + (size_t)(m0 + trow) * DH + tcol;
  const unsigned short* pB = Bt + (size_t)(n0 + (trow >> 5) * 64 + (trow & 31)) * DH + tcol;
  const int ldsW = wave * 512;          // lane-linear LDS dest base (elements)

  bf16x8 av[4][2];
  bf16x8 bv[2][2][2];
  f32x4 acc[8][4] = {};

  // prologue: buf0 <- tile0 full, buf1 <- tile1 {A0,B0,B1} (14 loads); VMW6
  // retires buf0's 8, leaves buf1's 6 in flight (buf1.A1 staged at P1 of iter 0).
  ST_A(0, 0, 0); ST_B(0, 0, 0); ST_B(0, 1, 0); ST_A(0, 1, 0);
  ST_A(1, 0, 1); ST_B(1, 0, 1); ST_B(1, 1, 1);
  VMW6; BAR;

#pragma unroll 1
  for (int i = 0; i < 15; ++i) {
    const int t1 = 2 * i + 1, t2 = 2 * i + 2, t3 = 2 * i + 3;
    // ---- K-tile 2i in buf0 ----
    RD_A(0, 0); RD_B(0, 0); ST_A(1, 1, t1); LGK8; BAR; LGK0; MM(0, 0); BAR;  // P1
    RD_B(0, 1);             ST_A(0, 0, t2);       BAR; LGK0; MM(0, 1); BAR;  // P2
    RD_A(0, 1);             ST_B(0, 0, t2);       BAR; LGK0; MM(1, 0); BAR;  // P3
                            ST_B(0, 1, t2); VMW6; BAR;       MM(1, 1); BAR;  // P4
    // ---- K-tile 2i+1 in buf1 ----
    RD_A(1, 0); RD_B(1, 0); ST_A(0, 1, t2); LGK8; BAR; LGK0; MM(0, 0); BAR;  // P5
    RD_B(1, 1);             ST_A(1, 0, t3);       BAR; LGK0; MM(0, 1); BAR;  // P6
    RD_A(1, 1);             ST_B(1, 0, t3);       BAR; LGK0; MM(1, 0); BAR;  // P7
                            ST_B(1, 1, t3); VMW6; BAR;       MM(1, 1); BAR;  // P8
  }
  // peel: tiles 30 (buf0, already retired) and 31 (buf1; A1 staged here).
  RD_A(0, 0); RD_B(0, 0); ST_A(1, 1, 31); LGK8; BAR; LGK0; MM(0, 0); BAR;
  RD_B(0, 1);                                   BAR; LGK0; MM(0, 1); BAR;
  RD_A(0, 1);                                   BAR; LGK0; MM(1, 0); BAR;
                                          VMW0; BAR;       MM(1, 1); BAR;
  RD_A(1, 0); RD_B(1, 0);                       BAR; LGK0; MM(0, 0); BAR;
  RD_B(1, 1);                                   BAR; LGK0; MM(0, 1); BAR;
  RD_A(1, 1);                                   BAR; LGK0; MM(1, 0); BAR;
                                                           MM(1, 1);

  const int mbase = m0 + wm * 128;
  const int nbase = n0 + wn * 64;

  if (nblk >= 8 && nblk < 16) {
    float w12 = (q == 3) ? 1.0f : (q == 2) ? 0.81450625f
              : (q == 1) ? 0.66342043f : 0.54036009f;   // 0.95^(12-4*q)
    w12 *= 0.05f;
#pragma unroll
    for (int mi = 0; mi < 8; ++mi) {
      const int mrow = mbase + mi * 16;
      const int bb = mrow >> 11;
      const int chh = (mrow >> 4) & (NCH - 1);
      const bool first = (chh == 0);
#pragma unroll
      for (int ni = 0; ni < 4; ++ni) {
        float v0 = acc[mi][ni][0];
        float s = ((v0 * 0.95f + acc[mi][ni][1]) * 0.95f + acc[mi][ni][2]) * 0.95f
                  + acc[mi][ni][3];
        if (first && q == 0) s += 19.0f * 0.857375f * v0;  // row0 coef -> 0.95^15
        s *= w12;
        s += __shfl_xor(s, 16);
        s += __shfl_xor(s, 32);
        if (q == 0) {
          int nloc = nbase + ni * 16 + rA - 2048;
          cpb[((size_t)bb * NCH + chh) * DH + nloc] = f2bf(s);
        }
      }
    }
  }

#pragma unroll
  for (int mi = 0; mi < 8; ++mi) {
#pragma unroll
    for (int rg = 0; rg < 4; ++rg) {
      const int m = mbase + mi * 16 + q * 4 + rg;
#pragma unroll
      for (int ni = 0; ni < 4; ++ni) {
        const int n = nbase + ni * 16 + rA;
        Z[(size_t)m * NZ + n] = f2bf(acc[mi][ni][rg]);
      }
    }
  }
}

#undef BAR
#undef VMW6
#undef VMW0
#undef LGK8
#undef LGK0
#undef ST_A
#undef ST_B
#undef RD_A
#undef RD_B
#undef MM

// ---- prefix level 1: within-group (16 chunks) relative prefix + group totals ----
__global__ __launch_bounds__(256) void zi_p1(unsigned short* __restrict__ cpb,
                                             float* __restrict__ gc) {
  int gid = blockIdx.x * 256 + threadIdx.x;   // (b, g, n): 4*8*2048 = 65536
  int n = gid & (DH - 1);
  int g = (gid >> 11) & 7;
  int b = gid >> 14;
  float run = 0.f;
#pragma unroll
  for (int j = 0; j < 16; ++j) {
    size_t idx = ((size_t)b * NCH + g * 16 + j) * DH + n;
    float c = bf2f(cpb[idx]);
    cpb[idx] = f2bf(run);
    run = c + LAM * run;
  }
  gc[((size_t)b * 8 + g) * DH + n] = run;
}

// ---- prefix level 2: scan group totals in place -> carry INTO each group ----
__global__ __launch_bounds__(256) void zi_p2(float* __restrict__ gc) {
  int gid = blockIdx.x * 256 + threadIdx.x;   // (b, n): 8192
  int n = gid & (DH - 1);
  int b = gid >> 11;
  float run = 0.f;
#pragma unroll
  for (int g = 0; g < 8; ++g) {
    size_t idx = ((size_t)b * 8 + g) * DH + n;
    float old = gc[idx];
    gc[idx] = run;
    run = old + LAM2 * run;
  }
}

// ---- final: out = g0*Zp + g1*EMA(Zi) + g2*(Zd - Zd_prev) + cc*kvWd + bias ----
__global__ __launch_bounds__(256) void final_combine(const unsigned short* __restrict__ Z,
                                                     const float* __restrict__ rs,
                                                     const unsigned short* __restrict__ cpb,
                                                     const float* __restrict__ gc,
                                                     const float* __restrict__ kvWd,
                                                     const float* __restrict__ bias,
                                                     float* __restrict__ out) {
  int tid = threadIdx.x;
  int n = blockIdx.y * 1024 + tid * 4;  // 4 cols/thread
  int ch = blockIdx.x & (NCH - 1);      // grid (512, 2)
  int b = blockIdx.x >> 7;
  int r0 = b * TT + ch * LCH;
  const unsigned short* zb = Z + (size_t)r0 * NZ + n;
  const bool first_chunk = (ch == 0);

  int g = ch >> 4, j = ch & 15;
  float pw = 1.f;
  for (int i = 0; i < j; ++i) pw *= LAM;
  float Pv[4];
  {
    union { unsigned short u[4]; uint2 v; } c;
    c.v = *(const uint2*)&cpb[((size_t)b * NCH + ch) * DH + n];
    float4 gp = *(const float4*)&gc[((size_t)b * 8 + g) * DH + n];
    float gpa[4] = {gp.x, gp.y, gp.z, gp.w};
#pragma unroll
    for (int i = 0; i < 4; ++i) Pv[i] = bf2f(c.u[i]) + pw * gpa[i];
  }
  float kv[4], bz[4];
  {
    float4 k0 = *(const float4*)&kvWd[n];
    float4 b0 = *(const float4*)&bias[n];
    kv[0]=k0.x; kv[1]=k0.y; kv[2]=k0.z; kv[3]=k0.w;
    bz[0]=b0.x; bz[1]=b0.y; bz[2]=b0.z; bz[3]=b0.w;
  }
  float zdp[4];
  if (!first_chunk) {
    union { unsigned short u[4]; uint2 v; } c;
    c.v = *(const uint2*)(zb - NZ + 2 * DH);
#pragma unroll
    for (int i = 0; i < 4; ++i) zdp[i] = bf2f(c.u[i]);
  } else {
#pragma unroll
    for (int i = 0; i < 4; ++i) zdp[i] = 0.f;
  }
  float J[4];
#pragma unroll
  for (int i = 0; i < 4; ++i) J[i] = 0.f;
  float f = 1.f;
  uint2 cp = *(const uint2*)(zb);
  uint2 ci = *(const uint2*)(zb + DH);
  uint2 cd = *(const uint2*)(zb + 2 * DH);
#pragma unroll
  for (int tau = 0; tau < LCH; ++tau) {
    uint2 np, ni, nd;
    if (tau < LCH - 1) {
      const unsigned short* zn = zb + (size_t)(tau + 1) * NZ;
      np = *(const uint2*)(zn);
      ni = *(const uint2*)(zn + DH);
      nd = *(const uint2*)(zn + 2 * DH);
    }
    float4 gg = *(const float4*)&rs[(size_t)(r0 + tau) * 4];
    union { unsigned short u[4]; uint2 v; } up, ui, ud;
    up.v = cp; ui.v = ci; ud.v = cd;
    const bool vfirst = first_chunk && (tau == 0);
    f *= 0.95f;
    float o[4];
#pragma unroll
    for (int i = 0; i < 4; ++i) {
      float xp = bf2f(up.u[i]), xi = bf2f(ui.u[i]), xd = bf2f(ud.u[i]);
      if (vfirst) J[i] = xi;
      else J[i] = 0.95f * J[i] + 0.05f * xi;
      float I = J[i] + f * Pv[i];
      float diff = vfirst ? 0.f : (xd - zdp[i]);
      o[i] = gg.x * xp + gg.y * I + gg.z * diff + gg.w * kv[i] + bz[i];
      zdp[i] = xd;
    }
    *(float4*)(out + (size_t)(r0 + tau) * DH + n) = make_float4(o[0], o[1], o[2], o[3]);
    cp = np; ci = ni; cd = nd;
  }
}

extern "C" void kernel_launch(void* const* d_in, const int* in_sizes, int n_in,
                              void* d_out, int out_size, void* d_ws, size_t ws_size,
                              hipStream_t stream) {
  const float* x        = (const float*)d_in[0];
  const float* Wp       = (const float*)d_in[1];
  const float* Wi       = (const float*)d_in[2];
  const float* Wd       = (const float*)d_in[3];
  const float* gate_w   = (const float*)d_in[4];
  const float* gate_b   = (const float*)d_in[5];
  const float* kick_vec = (const float*)d_in[6];
  const float* kick_w   = (const float*)d_in[7];
  const float* kick_b   = (const float*)d_in[8];
  const float* bias     = (const float*)d_in[9];
  float* out = (float*)d_out;

  char* ws = (char*)d_ws;
  unsigned short* Wt  = (unsigned short*)(ws + 0);           // 6144*2048*2  = 25,165,824
  unsigned short* Z   = (unsigned short*)(ws + 25165824);    // 8192*6144*2  = 100,663,296
  float* rs   = (float*)(ws + 125829120);                    // 8192*4*4     = 131,072
  float* kvWd = (float*)(ws + 125960192);                    // 2048*4       = 8,192
  unsigned short* cpb = (unsigned short*)(ws + 125968384);   // 4*128*2048*2 = 2,097,152
  float* gc   = (float*)(ws + 128065536);                    // 4*8*2048*4   = 262,144
  unsigned short* A = (unsigned short*)d_out;
  (void)ws_size; (void)in_sizes; (void)n_in; (void)out_size;

  hipMemsetAsync(kvWd, 0, DH * sizeof(float), stream);
  prep_w<<<dim3(3072), dim3(256), 0, stream>>>(Wp, Wi, Wd, kick_vec, Wt, kvWd);
  conv_x<<<dim3(8192), dim3(256), 0, stream>>>(x, gate_w, gate_b, kick_w, kick_b, rs, A);
  gemm_kernel<<<dim3(768), dim3(512), 0, stream>>>(A, Wt, Z, cpb);
  zi_p1<<<dim3(256), dim3(256), 0, stream>>>(cpb, gc);
  zi_p2<<<dim3(32), dim3(256), 0, stream>>>(gc);
  final_combine<<<dim3(512, 2), dim3(256), 0, stream>>>(Z, rs, cpb, gc, kvWd, bias, out);
}

// Round 4
// 373.283 us; speedup vs baseline: 1.1398x; 1.0454x over previous
//
#include <hip/hip_runtime.h>

#define DH 2048               // d_in = d_out = K of GEMM
#define TT 2048
#define BB 4
#define MROWS 8192            // B*T
#define NZ 6144               // GEMM N = 3*DH
#define NCH 128               // scan chunks over T
#define LCH 16                // chunk length
#define LAM 0.44012667f       // 0.95^16
#define LAM2 1.982646e-06f    // 0.95^256

typedef __attribute__((ext_vector_type(8))) short bf16x8;
typedef __attribute__((ext_vector_type(4))) float f32x4;

__device__ __forceinline__ unsigned short f2bf(float f) {
  union { float f; unsigned int u; } v; v.f = f;
  unsigned int u = v.u;
  return (unsigned short)((u + 0x7FFFu + ((u >> 16) & 1u)) >> 16);
}
__device__ __forceinline__ float bf2f(unsigned short u) {
  union { unsigned int i; float f; } v; v.i = ((unsigned int)u) << 16;
  return v.f;
}
__device__ __forceinline__ void gld16(const unsigned short* g, unsigned short* l) {
  __builtin_amdgcn_global_load_lds((const __attribute__((address_space(1))) void*)g,
                                   (__attribute__((address_space(3))) void*)l, 16, 0, 0);
}

// ---- Wt[n][k] = bf16(W[k][o]) with n = mat*2048+o; fused kvWd partials ----
__global__ __launch_bounds__(256) void prep_w(const float* __restrict__ Wp,
                                              const float* __restrict__ Wi,
                                              const float* __restrict__ Wd,
                                              const float* __restrict__ kick_vec,
                                              unsigned short* __restrict__ Wt,
                                              float* __restrict__ kvWd) {
  __shared__ float tile[64][65];
  int bid = blockIdx.x;                 // 3 * 32 * 32 = 3072
  int mat = bid >> 10;
  int t2 = bid & 1023;
  int dt = (t2 >> 5) * 64;
  int ot = (t2 & 31) * 64;
  const float* W = (mat == 0) ? Wp : ((mat == 1) ? Wi : Wd);
  int nbase = mat * DH;
  int tid = threadIdx.x;
  int r = tid >> 4;
  int c4 = (tid & 15) * 4;
#pragma unroll
  for (int i = 0; i < 4; ++i) {
    int rr = r + i * 16;
    float4 v = *(const float4*)&W[(size_t)(dt + rr) * DH + ot + c4];
    tile[rr][c4 + 0] = v.x; tile[rr][c4 + 1] = v.y;
    tile[rr][c4 + 2] = v.z; tile[rr][c4 + 3] = v.w;
  }
  __syncthreads();
  int o = tid >> 3;                     // 0..31
  int d8 = (tid & 7) * 8;
#pragma unroll
  for (int pass = 0; pass < 2; ++pass) {
    int oo = o + pass * 32;
    union { unsigned short u[8]; uint4 v; } pk;
#pragma unroll
    for (int i = 0; i < 8; ++i) pk.u[i] = f2bf(tile[d8 + i][oo]);
    *(uint4*)&Wt[(size_t)(nbase + ot + oo) * DH + dt + d8] = pk.v;
  }
  if (mat == 2 && tid < 64) {
    float s = 0.f;
#pragma unroll 8
    for (int dd = 0; dd < 64; ++dd) s += kick_vec[dt + dd] * tile[dd][tid];
    atomicAdd(&kvWd[ot + tid], s);
  }
}

// ---- fused rowstats + bf16(x) conversion (A staged in d_out) ----
__global__ __launch_bounds__(256) void conv_x(const float* __restrict__ x,
                                              const float* __restrict__ gate_w,
                                              const float* __restrict__ gate_b,
                                              const float* __restrict__ kick_w,
                                              const float* __restrict__ kick_b,
                                              float* __restrict__ rs,
                                              unsigned short* __restrict__ A) {
  int r = blockIdx.x;                   // 8192
  int t = r & (TT - 1);
  const float* xr = x + (size_t)r * DH;
  const float* xq = xr - DH;
  const bool hp = (t != 0);
  int tid = threadIdx.x;
  float a0 = 0, a1 = 0, a2 = 0, ak = 0, axx = 0, apx = 0, app = 0;
#pragma unroll
  for (int it = 0; it < 2; ++it) {
    int d0 = (tid + it * 256) * 4;
    float4 xv = *(const float4*)(xr + d0);
    float4 pv = hp ? *(const float4*)(xq + d0) : make_float4(0.f, 0.f, 0.f, 0.f);
    float4 q0 = *(const float4*)(gate_w + (size_t)d0 * 3);
    float4 q1 = *(const float4*)(gate_w + (size_t)d0 * 3 + 4);
    float4 q2 = *(const float4*)(gate_w + (size_t)d0 * 3 + 8);
    float4 kw = *(const float4*)(kick_w + d0);
    float xa[4] = {xv.x, xv.y, xv.z, xv.w};
    float pa[4] = {pv.x, pv.y, pv.z, pv.w};
    a0 += xa[0] * q0.x + xa[1] * q0.w + xa[2] * q1.z + xa[3] * q2.y;
    a1 += xa[0] * q0.y + xa[1] * q1.x + xa[2] * q1.w + xa[3] * q2.z;
    a2 += xa[0] * q0.z + xa[1] * q1.y + xa[2] * q2.x + xa[3] * q2.w;
    ak += xa[0] * kw.x + xa[1] * kw.y + xa[2] * kw.z + xa[3] * kw.w;
    union { unsigned short u[4]; uint2 v; } pk;
#pragma unroll
    for (int j = 0; j < 4; ++j) {
      axx += xa[j] * xa[j];
      apx += xa[j] * pa[j];
      app += pa[j] * pa[j];
      pk.u[j] = f2bf(xa[j]);
    }
    *(uint2*)&A[(size_t)r * DH + d0] = pk.v;
  }
#pragma unroll
  for (int off = 32; off > 0; off >>= 1) {
    a0 += __shfl_xor(a0, off); a1 += __shfl_xor(a1, off);
    a2 += __shfl_xor(a2, off); ak += __shfl_xor(ak, off);
    axx += __shfl_xor(axx, off); apx += __shfl_xor(apx, off);
    app += __shfl_xor(app, off);
  }
  __shared__ float red[4][7];
  int wv = tid >> 6;
  if ((tid & 63) == 0) {
    red[wv][0] = a0; red[wv][1] = a1; red[wv][2] = a2; red[wv][3] = ak;
    red[wv][4] = axx; red[wv][5] = apx; red[wv][6] = app;
  }
  __syncthreads();
  if (tid == 0) {
    float v[7];
#pragma unroll
    for (int i = 0; i < 7; ++i) v[i] = red[0][i] + red[1][i] + red[2][i] + red[3][i];
    float l0 = v[0] + gate_b[0], l1 = v[1] + gate_b[1], l2 = v[2] + gate_b[2];
    float mx = fmaxf(l0, fmaxf(l1, l2));
    float e0 = expf(l0 - mx), e1 = expf(l1 - mx), e2 = expf(l2 - mx);
    float inv = 1.f / (e0 + e1 + e2);
    float G0 = fminf(e0 * inv, 0.6f);
    float G1 = fminf(e1 * inv, 0.6f);
    float G2 = fminf(e2 * inv, 0.6f);
    G1 = fmaxf(G1, 0.25f);
    float inv2 = 1.f / (G0 + G1 + G2);
    G0 *= inv2; G1 *= inv2; G2 *= inv2;
    float ks = 1.f / (1.f + expf(-(v[3] + kick_b[0])));
    float nn = fmaxf(sqrtf(v[4]), 1e-12f) * fmaxf(sqrtf(v[6]), 1e-12f);
    float cs = hp ? (v[5] / nn) : 0.f;
    float cc = (cs > 0.95f) ? (G2 * ks) : 0.f;
    *(float4*)(rs + (size_t)r * 4) = make_float4(G0, G1, G2, cc);
  }
}

// ---- GEMM: 256x256 tile, BK=64, 8 waves, 8-phase ONE-barrier schedule ----
// Phase = [ds_read][vmw?][BAR][LGK0][MM][stage]. The trailing barrier is removed:
// the rotation guarantees each stage targets a region whose last read was in a
// strictly earlier phase, so the phase's LEADING barrier (which all waves reach
// only after the previous phase's LGK0) is the read-complete rendezvous.
// Per-wave VMW sits BEFORE a barrier -> global retirement guarantee.
// Steady state: VMW4 at P4 (12 outstanding, retires through P1 = buf1 complete)
// and VMW4 at P8 (12 outstanding, retires through P5 = buf0 complete).

#define BAR __builtin_amdgcn_s_barrier()
#define VMW6 asm volatile("s_waitcnt vmcnt(6)" ::: "memory")
#define VMW4 asm volatile("s_waitcnt vmcnt(4)" ::: "memory")
#define VMW0 asm volatile("s_waitcnt vmcnt(0)" ::: "memory")
#define LGK8 asm volatile("s_waitcnt lgkmcnt(8)" ::: "memory")
#define LGK0 asm volatile("s_waitcnt lgkmcnt(0)" ::: "memory")

#define ST_A(bf, h, kt) do { \
  gld16(pA + (size_t)((h) * 64) * DH + (kt) * 64,       lA + (bf) * 16384 + (h) * 8192 + ldsW); \
  gld16(pA + (size_t)((h) * 64 + 128) * DH + (kt) * 64, lA + (bf) * 16384 + (h) * 8192 + 4096 + ldsW); \
} while (0)
#define ST_B(bf, g, kt) do { \
  gld16(pB + (size_t)((g) * 32) * DH + (kt) * 64,       lB + (bf) * 16384 + (g) * 8192 + ldsW); \
  gld16(pB + (size_t)((g) * 32 + 128) * DH + (kt) * 64, lB + (bf) * 16384 + (g) * 8192 + 4096 + ldsW); \
} while (0)

#define RD_A(bf, h) do { \
  const unsigned short* p_ = lA + (bf) * 16384 + (h) * 8192 + aRd; \
  _Pragma("unroll") \
  for (int mi_ = 0; mi_ < 4; ++mi_) { \
    av[mi_][0] = *(const bf16x8*)(p_ + mi_ * 1024 + kph0); \
    av[mi_][1] = *(const bf16x8*)(p_ + mi_ * 1024 + kph1); \
  } \
} while (0)
#define RD_B(bf, g) do { \
  const unsigned short* p_ = lB + (bf) * 16384 + (g) * 8192 + bRd; \
  _Pragma("unroll") \
  for (int ni_ = 0; ni_ < 2; ++ni_) { \
    bv[g][ni_][0] = *(const bf16x8*)(p_ + ni_ * 1024 + kph0); \
    bv[g][ni_][1] = *(const bf16x8*)(p_ + ni_ * 1024 + kph1); \
  } \
} while (0)

#define MM(h, g) do { \
  __builtin_amdgcn_s_setprio(1); \
  _Pragma("unroll") \
  for (int mi_ = 0; mi_ < 4; ++mi_) { \
    _Pragma("unroll") \
    for (int ni_ = 0; ni_ < 2; ++ni_) { \
      f32x4 c_ = acc[(h) * 4 + mi_][(g) * 2 + ni_]; \
      c_ = __builtin_amdgcn_mfma_f32_16x16x32_bf16(av[mi_][0], bv[g][ni_][0], c_, 0, 0, 0); \
      c_ = __builtin_amdgcn_mfma_f32_16x16x32_bf16(av[mi_][1], bv[g][ni_][1], c_, 0, 0, 0); \
      acc[(h) * 4 + mi_][(g) * 2 + ni_] = c_; \
    } \
  } \
  __builtin_amdgcn_s_setprio(0); \
} while (0)

__global__ __launch_bounds__(512, 2) void gemm_kernel(const unsigned short* __restrict__ A,
                                                      const unsigned short* __restrict__ Bt,
                                                      unsigned short* __restrict__ Z,
                                                      unsigned short* __restrict__ cpb) {
  __shared__ __align__(16) unsigned short lA[2 * 16384];
  __shared__ __align__(16) unsigned short lB[2 * 16384];
  const int tid = threadIdx.x;          // 0..511
  const int wave = tid >> 6, lane = tid & 63;
  const int bid = blockIdx.x;           // 768 = 32 mblk * 24 nblk
  const int xcd = bid & 7;
  const int loc = bid >> 3;             // 0..95
  const int mblk = xcd * 4 + (loc & 3); // 0..31
  const int nblk = loc >> 2;            // 0..23
  const int m0 = mblk * 256, n0 = nblk * 256;

  const int wm = wave >> 2, wn = wave & 3;      // wave tile: 128(M) x 64(N)
  const int rA = lane & 15, q = lane >> 4, sw = lane & 7;
  const int kph0 = ((0 + q) ^ sw) * 8;          // swizzled k-slot, kb=0
  const int kph1 = ((4 + q) ^ sw) * 8;          // kb=1
  const int aRd = wm * 4096 + rA * 64;
  const int bRd = wn * 2048 + rA * 64;

  const int trow = tid >> 3;            // 0..63
  const int tcol = ((tid & 7) ^ (trow & 7)) * 8;
  const unsigned short* pA = A + (size_t)(m0 + trow) * DH + tcol;
  const unsigned short* pB = Bt + (size_t)(n0 + (trow >> 5) * 64 + (trow & 31)) * DH + tcol;
  const int ldsW = wave * 512;          // lane-linear LDS dest base (elements)

  bf16x8 av[4][2];
  bf16x8 bv[2][2][2];
  f32x4 acc[8][4] = {};

  // prologue: buf0 <- tile0 full, buf1 <- tile1 {A0,B0,B1} (14 loads); VMW6
  // retires buf0's 8, leaves buf1's 6 in flight (buf1.A1 staged at P1 of iter 0).
  ST_A(0, 0, 0); ST_B(0, 0, 0); ST_B(0, 1, 0); ST_A(0, 1, 0);
  ST_A(1, 0, 1); ST_B(1, 0, 1); ST_B(1, 1, 1);
  VMW6; BAR;

#pragma unroll 1
  for (int i = 0; i < 15; ++i) {
    const int t1 = 2 * i + 1, t2 = 2 * i + 2, t3 = 2 * i + 3;
    // ---- K-tile 2i in buf0 ----
    RD_A(0, 0); RD_B(0, 0); LGK8; BAR; LGK0; MM(0, 0); ST_A(1, 1, t1);  // P1
    RD_B(0, 1);                   BAR; LGK0; MM(0, 1); ST_A(0, 0, t2);  // P2
    RD_A(0, 1);                   BAR; LGK0; MM(1, 0); ST_B(0, 0, t2);  // P3
                            VMW4; BAR;       MM(1, 1); ST_B(0, 1, t2);  // P4
    // ---- K-tile 2i+1 in buf1 ----
    RD_A(1, 0); RD_B(1, 0); LGK8; BAR; LGK0; MM(0, 0); ST_A(0, 1, t2);  // P5
    RD_B(1, 1);                   BAR; LGK0; MM(0, 1); ST_A(1, 0, t3);  // P6
    RD_A(1, 1);                   BAR; LGK0; MM(1, 0); ST_B(1, 0, t3);  // P7
                            VMW4; BAR;       MM(1, 1); ST_B(1, 1, t3);  // P8
  }
  // peel: tiles 30 (buf0) and 31 (buf1); buf1.A1 staged at peel P1; one VMW0.
  RD_A(0, 0); RD_B(0, 0); LGK8; BAR; LGK0; MM(0, 0); ST_A(1, 1, 31);
  RD_B(0, 1);                   BAR; LGK0; MM(0, 1);
  RD_A(0, 1);                   BAR; LGK0; MM(1, 0);
                          VMW0; BAR;       MM(1, 1);
  RD_A(1, 0); RD_B(1, 0); LGK8; BAR; LGK0; MM(0, 0);
  RD_B(1, 1);                   BAR; LGK0; MM(0, 1);
  RD_A(1, 1);                   BAR; LGK0; MM(1, 0);
                                           MM(1, 1);

  const int mbase = m0 + wm * 128;
  const int nbase = n0 + wn * 64;

  if (nblk >= 8 && nblk < 16) {
    float w12 = (q == 3) ? 1.0f : (q == 2) ? 0.81450625f
              : (q == 1) ? 0.66342043f : 0.54036009f;   // 0.95^(12-4*q)
    w12 *= 0.05f;
#pragma unroll
    for (int mi = 0; mi < 8; ++mi) {
      const int mrow = mbase + mi * 16;
      const int bb = mrow >> 11;
      const int chh = (mrow >> 4) & (NCH - 1);
      const bool first = (chh == 0);
#pragma unroll
      for (int ni = 0; ni < 4; ++ni) {
        float v0 = acc[mi][ni][0];
        float s = ((v0 * 0.95f + acc[mi][ni][1]) * 0.95f + acc[mi][ni][2]) * 0.95f
                  + acc[mi][ni][3];
        if (first && q == 0) s += 19.0f * 0.857375f * v0;  // row0 coef -> 0.95^15
        s *= w12;
        s += __shfl_xor(s, 16);
        s += __shfl_xor(s, 32);
        if (q == 0) {
          int nloc = nbase + ni * 16 + rA - 2048;
          cpb[((size_t)bb * NCH + chh) * DH + nloc] = f2bf(s);
        }
      }
    }
  }

  // Z write: ni innermost so each (mi,rg) row's 128B line is completed by 4
  // temporally-adjacent stores (L2 merges -> clean HBM write lines).
#pragma unroll
  for (int mi = 0; mi < 8; ++mi) {
#pragma unroll
    for (int rg = 0; rg < 4; ++rg) {
      const int m = mbase + mi * 16 + q * 4 + rg;
#pragma unroll
      for (int ni = 0; ni < 4; ++ni) {
        const int n = nbase + ni * 16 + rA;
        Z[(size_t)m * NZ + n] = f2bf(acc[mi][ni][rg]);
      }
    }
  }
}

#undef BAR
#undef VMW6
#undef VMW4
#undef VMW0
#undef LGK8
#undef LGK0
#undef ST_A
#undef ST_B
#undef RD_A
#undef RD_B
#undef MM

// ---- prefix level 1: within-group (16 chunks) relative prefix + group totals ----
__global__ __launch_bounds__(256) void zi_p1(unsigned short* __restrict__ cpb,
                                             float* __restrict__ gc) {
  int gid = blockIdx.x * 256 + threadIdx.x;   // (b, g, n): 4*8*2048 = 65536
  int n = gid & (DH - 1);
  int g = (gid >> 11) & 7;
  int b = gid >> 14;
  float run = 0.f;
#pragma unroll
  for (int j = 0; j < 16; ++j) {
    size_t idx = ((size_t)b * NCH + g * 16 + j) * DH + n;
    float c = bf2f(cpb[idx]);
    cpb[idx] = f2bf(run);
    run = c + LAM * run;
  }
  gc[((size_t)b * 8 + g) * DH + n] = run;
}

// ---- prefix level 2: scan group totals in place -> carry INTO each group ----
__global__ __launch_bounds__(256) void zi_p2(float* __restrict__ gc) {
  int gid = blockIdx.x * 256 + threadIdx.x;   // (b, n): 8192
  int n = gid & (DH - 1);
  int b = gid >> 11;
  float run = 0.f;
#pragma unroll
  for (int g = 0; g < 8; ++g) {
    size_t idx = ((size_t)b * 8 + g) * DH + n;
    float old = gc[idx];
    gc[idx] = run;
    run = old + LAM2 * run;
  }
}

// ---- final: out = g0*Zp + g1*EMA(Zi) + g2*(Zd - Zd_prev) + cc*kvWd + bias ----
__global__ __launch_bounds__(256) void final_combine(const unsigned short* __restrict__ Z,
                                                     const float* __restrict__ rs,
                                                     const unsigned short* __restrict__ cpb,
                                                     const float* __restrict__ gc,
                                                     const float* __restrict__ kvWd,
                                                     const float* __restrict__ bias,
                                                     float* __restrict__ out) {
  int tid = threadIdx.x;
  int n = blockIdx.y * 1024 + tid * 4;  // 4 cols/thread
  int ch = blockIdx.x & (NCH - 1);      // grid (512, 2)
  int b = blockIdx.x >> 7;
  int r0 = b * TT + ch * LCH;
  const unsigned short* zb = Z + (size_t)r0 * NZ + n;
  const bool first_chunk = (ch == 0);

  int g = ch >> 4, j = ch & 15;
  float pw = 1.f;
  for (int i = 0; i < j; ++i) pw *= LAM;
  float Pv[4];
  {
    union { unsigned short u[4]; uint2 v; } c;
    c.v = *(const uint2*)&cpb[((size_t)b * NCH + ch) * DH + n];
    float4 gp = *(const float4*)&gc[((size_t)b * 8 + g) * DH + n];
    float gpa[4] = {gp.x, gp.y, gp.z, gp.w};
#pragma unroll
    for (int i = 0; i < 4; ++i) Pv[i] = bf2f(c.u[i]) + pw * gpa[i];
  }
  float kv[4], bz[4];
  {
    float4 k0 = *(const float4*)&kvWd[n];
    float4 b0 = *(const float4*)&bias[n];
    kv[0]=k0.x; kv[1]=k0.y; kv[2]=k0.z; kv[3]=k0.w;
    bz[0]=b0.x; bz[1]=b0.y; bz[2]=b0.z; bz[3]=b0.w;
  }
  float zdp[4];
  if (!first_chunk) {
    union { unsigned short u[4]; uint2 v; } c;
    c.v = *(const uint2*)(zb - NZ + 2 * DH);
#pragma unroll
    for (int i = 0; i < 4; ++i) zdp[i] = bf2f(c.u[i]);
  } else {
#pragma unroll
    for (int i = 0; i < 4; ++i) zdp[i] = 0.f;
  }
  float J[4];
#pragma unroll
  for (int i = 0; i < 4; ++i) J[i] = 0.f;
  float f = 1.f;
  uint2 cp = *(const uint2*)(zb);
  uint2 ci = *(const uint2*)(zb + DH);
  uint2 cd = *(const uint2*)(zb + 2 * DH);
#pragma unroll
  for (int tau = 0; tau < LCH; ++tau) {
    uint2 np, ni, nd;
    if (tau < LCH - 1) {
      const unsigned short* zn = zb + (size_t)(tau + 1) * NZ;
      np = *(const uint2*)(zn);
      ni = *(const uint2*)(zn + DH);
      nd = *(const uint2*)(zn + 2 * DH);
    }
    float4 gg = *(const float4*)&rs[(size_t)(r0 + tau) * 4];
    union { unsigned short u[4]; uint2 v; } up, ui, ud;
    up.v = cp; ui.v = ci; ud.v = cd;
    const bool vfirst = first_chunk && (tau == 0);
    f *= 0.95f;
    float o[4];
#pragma unroll
    for (int i = 0; i < 4; ++i) {
      float xp = bf2f(up.u[i]), xi = bf2f(ui.u[i]), xd = bf2f(ud.u[i]);
      if (vfirst) J[i] = xi;
      else J[i] = 0.95f * J[i] + 0.05f * xi;
      float I = J[i] + f * Pv[i];
      float diff = vfirst ? 0.f : (xd - zdp[i]);
      o[i] = gg.x * xp + gg.y * I + gg.z * diff + gg.w * kv[i] + bz[i];
      zdp[i] = xd;
    }
    *(float4*)(out + (size_t)(r0 + tau) * DH + n) = make_float4(o[0], o[1], o[2], o[3]);
    cp = np; ci = ni; cd = nd;
  }
}

extern "C" void kernel_launch(void* const* d_in, const int* in_sizes, int n_in,
                              void* d_out, int out_size, void* d_ws, size_t ws_size,
                              hipStream_t stream) {
  const float* x        = (const float*)d_in[0];
  const float* Wp       = (const float*)d_in[1];
  const float* Wi       = (const float*)d_in[2];
  const float* Wd       = (const float*)d_in[3];
  const float* gate_w   = (const float*)d_in[4];
  const float* gate_b   = (const float*)d_in[5];
  const float* kick_vec = (const float*)d_in[6];
  const float* kick_w   = (const float*)d_in[7];
  const float* kick_b   = (const float*)d_in[8];
  const float* bias     = (const float*)d_in[9];
  float* out = (float*)d_out;

  char* ws = (char*)d_ws;
  unsigned short* Wt  = (unsigned short*)(ws + 0);           // 6144*2048*2  = 25,165,824
  unsigned short* Z   = (unsigned short*)(ws + 25165824);    // 8192*6144*2  = 100,663,296
  float* rs   = (float*)(ws + 125829120);                    // 8192*4*4     = 131,072
  float* kvWd = (float*)(ws + 125960192);                    // 2048*4       = 8,192
  unsigned short* cpb = (unsigned short*)(ws + 125968384);   // 4*128*2048*2 = 2,097,152
  float* gc   = (float*)(ws + 128065536);                    // 4*8*2048*4   = 262,144
  unsigned short* A = (unsigned short*)d_out;
  (void)ws_size; (void)in_sizes; (void)n_in; (void)out_size;

  hipMemsetAsync(kvWd, 0, DH * sizeof(float), stream);
  prep_w<<<dim3(3072), dim3(256), 0, stream>>>(Wp, Wi, Wd, kick_vec, Wt, kvWd);
  conv_x<<<dim3(8192), dim3(256), 0, stream>>>(x, gate_w, gate_b, kick_w, kick_b, rs, A);
  gemm_kernel<<<dim3(768), dim3(512), 0, stream>>>(A, Wt, Z, cpb);
  zi_p1<<<dim3(256), dim3(256), 0, stream>>>(cpb, gc);
  zi_p2<<<dim3(32), dim3(256), 0, stream>>>(gc);
  final_combine<<<dim3(512, 2), dim3(256), 0, stream>>>(Z, rs, cpb, gc, kvWd, bias, out);
}

// Round 5
// 369.264 us; speedup vs baseline: 1.1522x; 1.0109x over previous
//
#include <hip/hip_runtime.h>

#define DH 2048               // d_in = d_out = K of GEMM
#define TT 2048
#define BB 4
#define MROWS 8192            // B*T
#define NZ 6144               // GEMM N = 3*DH
#define NCH 128               // scan chunks over T
#define LCH 16                // chunk length
#define LAM 0.44012667f       // 0.95^16
#define LAM2 1.982646e-06f    // 0.95^256

typedef __attribute__((ext_vector_type(8))) short bf16x8;
typedef __attribute__((ext_vector_type(4))) float f32x4;

__device__ __forceinline__ unsigned short f2bf(float f) {
  union { float f; unsigned int u; } v; v.f = f;
  unsigned int u = v.u;
  return (unsigned short)((u + 0x7FFFu + ((u >> 16) & 1u)) >> 16);
}
__device__ __forceinline__ float bf2f(unsigned short u) {
  union { unsigned int i; float f; } v; v.i = ((unsigned int)u) << 16;
  return v.f;
}
__device__ __forceinline__ void gld16(const unsigned short* g, unsigned short* l) {
  __builtin_amdgcn_global_load_lds((const __attribute__((address_space(1))) void*)g,
                                   (__attribute__((address_space(3))) void*)l, 16, 0, 0);
}

// ---- merged prep_w + conv_x (independent memory-bound passes overlap) ----
// bid < 3072: Wt[n][k] = bf16(W[k][o]) transpose + fused kvWd partials
// bid >= 3072: rowstats + bf16(x) conversion (A staged in d_out)
__global__ __launch_bounds__(256) void prep_conv(const float* __restrict__ Wp,
                                                 const float* __restrict__ Wi,
                                                 const float* __restrict__ Wd,
                                                 const float* __restrict__ kick_vec,
                                                 unsigned short* __restrict__ Wt,
                                                 float* __restrict__ kvWd,
                                                 const float* __restrict__ x,
                                                 const float* __restrict__ gate_w,
                                                 const float* __restrict__ gate_b,
                                                 const float* __restrict__ kick_w,
                                                 const float* __restrict__ kick_b,
                                                 float* __restrict__ rs,
                                                 unsigned short* __restrict__ A) {
  __shared__ float tile[64][65];
  __shared__ float red[4][7];
  int bid = blockIdx.x;
  int tid = threadIdx.x;
  if (bid < 3072) {
    int mat = bid >> 10;
    int t2 = bid & 1023;
    int dt = (t2 >> 5) * 64;
    int ot = (t2 & 31) * 64;
    const float* W = (mat == 0) ? Wp : ((mat == 1) ? Wi : Wd);
    int nbase = mat * DH;
    int r = tid >> 4;
    int c4 = (tid & 15) * 4;
#pragma unroll
    for (int i = 0; i < 4; ++i) {
      int rr = r + i * 16;
      float4 v = *(const float4*)&W[(size_t)(dt + rr) * DH + ot + c4];
      tile[rr][c4 + 0] = v.x; tile[rr][c4 + 1] = v.y;
      tile[rr][c4 + 2] = v.z; tile[rr][c4 + 3] = v.w;
    }
    __syncthreads();
    int o = tid >> 3;                     // 0..31
    int d8 = (tid & 7) * 8;
#pragma unroll
    for (int pass = 0; pass < 2; ++pass) {
      int oo = o + pass * 32;
      union { unsigned short u[8]; uint4 v; } pk;
#pragma unroll
      for (int i = 0; i < 8; ++i) pk.u[i] = f2bf(tile[d8 + i][oo]);
      *(uint4*)&Wt[(size_t)(nbase + ot + oo) * DH + dt + d8] = pk.v;
    }
    if (mat == 2 && tid < 64) {
      float s = 0.f;
#pragma unroll 8
      for (int dd = 0; dd < 64; ++dd) s += kick_vec[dt + dd] * tile[dd][tid];
      atomicAdd(&kvWd[ot + tid], s);
    }
    return;
  }
  // ---- conv_x path ----
  int r = bid - 3072;                   // 8192
  int t = r & (TT - 1);
  const float* xr = x + (size_t)r * DH;
  const float* xq = xr - DH;
  const bool hp = (t != 0);
  float a0 = 0, a1 = 0, a2 = 0, ak = 0, axx = 0, apx = 0, app = 0;
#pragma unroll
  for (int it = 0; it < 2; ++it) {
    int d0 = (tid + it * 256) * 4;
    float4 xv = *(const float4*)(xr + d0);
    float4 pv = hp ? *(const float4*)(xq + d0) : make_float4(0.f, 0.f, 0.f, 0.f);
    float4 q0 = *(const float4*)(gate_w + (size_t)d0 * 3);
    float4 q1 = *(const float4*)(gate_w + (size_t)d0 * 3 + 4);
    float4 q2 = *(const float4*)(gate_w + (size_t)d0 * 3 + 8);
    float4 kw = *(const float4*)(kick_w + d0);
    float xa[4] = {xv.x, xv.y, xv.z, xv.w};
    float pa[4] = {pv.x, pv.y, pv.z, pv.w};
    a0 += xa[0] * q0.x + xa[1] * q0.w + xa[2] * q1.z + xa[3] * q2.y;
    a1 += xa[0] * q0.y + xa[1] * q1.x + xa[2] * q1.w + xa[3] * q2.z;
    a2 += xa[0] * q0.z + xa[1] * q1.y + xa[2] * q2.x + xa[3] * q2.w;
    ak += xa[0] * kw.x + xa[1] * kw.y + xa[2] * kw.z + xa[3] * kw.w;
    union { unsigned short u[4]; uint2 v; } pk;
#pragma unroll
    for (int j = 0; j < 4; ++j) {
      axx += xa[j] * xa[j];
      apx += xa[j] * pa[j];
      app += pa[j] * pa[j];
      pk.u[j] = f2bf(xa[j]);
    }
    *(uint2*)&A[(size_t)r * DH + d0] = pk.v;
  }
#pragma unroll
  for (int off = 32; off > 0; off >>= 1) {
    a0 += __shfl_xor(a0, off); a1 += __shfl_xor(a1, off);
    a2 += __shfl_xor(a2, off); ak += __shfl_xor(ak, off);
    axx += __shfl_xor(axx, off); apx += __shfl_xor(apx, off);
    app += __shfl_xor(app, off);
  }
  int wv = tid >> 6;
  if ((tid & 63) == 0) {
    red[wv][0] = a0; red[wv][1] = a1; red[wv][2] = a2; red[wv][3] = ak;
    red[wv][4] = axx; red[wv][5] = apx; red[wv][6] = app;
  }
  __syncthreads();
  if (tid == 0) {
    float v[7];
#pragma unroll
    for (int i = 0; i < 7; ++i) v[i] = red[0][i] + red[1][i] + red[2][i] + red[3][i];
    float l0 = v[0] + gate_b[0], l1 = v[1] + gate_b[1], l2 = v[2] + gate_b[2];
    float mx = fmaxf(l0, fmaxf(l1, l2));
    float e0 = expf(l0 - mx), e1 = expf(l1 - mx), e2 = expf(l2 - mx);
    float inv = 1.f / (e0 + e1 + e2);
    float G0 = fminf(e0 * inv, 0.6f);
    float G1 = fminf(e1 * inv, 0.6f);
    float G2 = fminf(e2 * inv, 0.6f);
    G1 = fmaxf(G1, 0.25f);
    float inv2 = 1.f / (G0 + G1 + G2);
    G0 *= inv2; G1 *= inv2; G2 *= inv2;
    float ks = 1.f / (1.f + expf(-(v[3] + kick_b[0])));
    float nn = fmaxf(sqrtf(v[4]), 1e-12f) * fmaxf(sqrtf(v[6]), 1e-12f);
    float cs = hp ? (v[5] / nn) : 0.f;
    float cc = (cs > 0.95f) ? (G2 * ks) : 0.f;
    *(float4*)(rs + (size_t)r * 4) = make_float4(G0, G1, G2, cc);
  }
}

// ---- GEMM: 256x256 tile, BK=64, 8 waves, 8-phase one-barrier schedule ----
// Phase = [ds_read][vmw?][BAR][stage][LGK0][MM]. Stage moved to post-BAR/pre-MM:
// loads enter flight before the MFMA burst and drain under it.
// WAR: every ST@p targets a region read at phase <= p-1; any wave past BAR(p)
// completed LGK0(p-1)+MM(p-1), so those reads are in registers.
// RAW: VMW4 at P4 (14 outstanding -> retires 10 = through P1 = buf1 complete)
// and VMW4 at P8 (retires through P5 = buf0 complete); VMW before BAR globalizes.

#define BAR __builtin_amdgcn_s_barrier()
#define VMW6 asm volatile("s_waitcnt vmcnt(6)" ::: "memory")
#define VMW4 asm volatile("s_waitcnt vmcnt(4)" ::: "memory")
#define VMW0 asm volatile("s_waitcnt vmcnt(0)" ::: "memory")
#define LGK0 asm volatile("s_waitcnt lgkmcnt(0)" ::: "memory")

#define ST_A(bf, h, kt) do { \
  gld16(pA + (size_t)((h) * 64) * DH + (kt) * 64,       lA + (bf) * 16384 + (h) * 8192 + ldsW); \
  gld16(pA + (size_t)((h) * 64 + 128) * DH + (kt) * 64, lA + (bf) * 16384 + (h) * 8192 + 4096 + ldsW); \
} while (0)
#define ST_B(bf, g, kt) do { \
  gld16(pB + (size_t)((g) * 32) * DH + (kt) * 64,       lB + (bf) * 16384 + (g) * 8192 + ldsW); \
  gld16(pB + (size_t)((g) * 32 + 128) * DH + (kt) * 64, lB + (bf) * 16384 + (g) * 8192 + 4096 + ldsW); \
} while (0)

#define RD_A(bf, h) do { \
  const unsigned short* p_ = lA + (bf) * 16384 + (h) * 8192 + aRd; \
  _Pragma("unroll") \
  for (int mi_ = 0; mi_ < 4; ++mi_) { \
    av[mi_][0] = *(const bf16x8*)(p_ + mi_ * 1024 + kph0); \
    av[mi_][1] = *(const bf16x8*)(p_ + mi_ * 1024 + kph1); \
  } \
} while (0)
#define RD_B(bf, g) do { \
  const unsigned short* p_ = lB + (bf) * 16384 + (g) * 8192 + bRd; \
  _Pragma("unroll") \
  for (int ni_ = 0; ni_ < 2; ++ni_) { \
    bv[g][ni_][0] = *(const bf16x8*)(p_ + ni_ * 1024 + kph0); \
    bv[g][ni_][1] = *(const bf16x8*)(p_ + ni_ * 1024 + kph1); \
  } \
} while (0)

#define MM(h, g) do { \
  __builtin_amdgcn_s_setprio(1); \
  _Pragma("unroll") \
  for (int mi_ = 0; mi_ < 4; ++mi_) { \
    _Pragma("unroll") \
    for (int ni_ = 0; ni_ < 2; ++ni_) { \
      f32x4 c_ = acc[(h) * 4 + mi_][(g) * 2 + ni_]; \
      c_ = __builtin_amdgcn_mfma_f32_16x16x32_bf16(av[mi_][0], bv[g][ni_][0], c_, 0, 0, 0); \
      c_ = __builtin_amdgcn_mfma_f32_16x16x32_bf16(av[mi_][1], bv[g][ni_][1], c_, 0, 0, 0); \
      acc[(h) * 4 + mi_][(g) * 2 + ni_] = c_; \
    } \
  } \
  __builtin_amdgcn_s_setprio(0); \
} while (0)

__global__ __launch_bounds__(512, 2) void gemm_kernel(const unsigned short* __restrict__ A,
                                                      const unsigned short* __restrict__ Bt,
                                                      unsigned short* __restrict__ Z,
                                                      unsigned short* __restrict__ cpb) {
  __shared__ __align__(16) unsigned short lA[2 * 16384];
  __shared__ __align__(16) unsigned short lB[2 * 16384];
  const int tid = threadIdx.x;          // 0..511
  const int wave = tid >> 6, lane = tid & 63;
  const int bid = blockIdx.x;           // 768 = 32 mblk * 24 nblk
  const int xcd = bid & 7;
  const int loc = bid >> 3;             // 0..95
  const int mblk = xcd * 4 + (loc & 3); // 0..31
  const int nblk = loc >> 2;            // 0..23
  const int m0 = mblk * 256, n0 = nblk * 256;

  const int wm = wave >> 2, wn = wave & 3;      // wave tile: 128(M) x 64(N)
  const int rA = lane & 15, q = lane >> 4, sw = lane & 7;
  const int kph0 = ((0 + q) ^ sw) * 8;          // swizzled k-slot, kb=0
  const int kph1 = ((4 + q) ^ sw) * 8;          // kb=1
  const int aRd = wm * 4096 + rA * 64;
  const int bRd = wn * 2048 + rA * 64;

  const int trow = tid >> 3;            // 0..63
  const int tcol = ((tid & 7) ^ (trow & 7)) * 8;
  const unsigned short* pA = A + (size_t)(m0 + trow) * DH + tcol;
  const unsigned short* pB = Bt + (size_t)(n0 + (trow >> 5) * 64 + (trow & 31)) * DH + tcol;
  const int ldsW = wave * 512;          // lane-linear LDS dest base (elements)

  bf16x8 av[4][2];
  bf16x8 bv[2][2][2];
  f32x4 acc[8][4] = {};

  // prologue: buf0 <- tile0 full, buf1 <- tile1 {A0,B0,B1} (14 loads); VMW6
  // retires buf0's 8, leaves buf1's 6 in flight (buf1.A1 staged at P1 of iter 0).
  ST_A(0, 0, 0); ST_B(0, 0, 0); ST_B(0, 1, 0); ST_A(0, 1, 0);
  ST_A(1, 0, 1); ST_B(1, 0, 1); ST_B(1, 1, 1);
  VMW6; BAR;

#pragma unroll 1
  for (int i = 0; i < 15; ++i) {
    const int t1 = 2 * i + 1, t2 = 2 * i + 2, t3 = 2 * i + 3;
    // ---- K-tile 2i in buf0 ----
    RD_A(0, 0); RD_B(0, 0); BAR; ST_A(1, 1, t1); LGK0; MM(0, 0);  // P1
    RD_B(0, 1);             BAR; ST_A(0, 0, t2); LGK0; MM(0, 1);  // P2
    RD_A(0, 1);             BAR; ST_B(0, 0, t2); LGK0; MM(1, 0);  // P3
                      VMW4; BAR; ST_B(0, 1, t2);       MM(1, 1);  // P4
    // ---- K-tile 2i+1 in buf1 ----
    RD_A(1, 0); RD_B(1, 0); BAR; ST_A(0, 1, t2); LGK0; MM(0, 0);  // P5
    RD_B(1, 1);             BAR; ST_A(1, 0, t3); LGK0; MM(0, 1);  // P6
    RD_A(1, 1);             BAR; ST_B(1, 0, t3); LGK0; MM(1, 0);  // P7
                      VMW4; BAR; ST_B(1, 1, t3);       MM(1, 1);  // P8
  }
  // peel: tiles 30 (buf0) and 31 (buf1); buf1.A1 staged at peel P1; one VMW0.
  RD_A(0, 0); RD_B(0, 0); BAR; ST_A(1, 1, 31); LGK0; MM(0, 0);
  RD_B(0, 1);             BAR;                 LGK0; MM(0, 1);
  RD_A(0, 1);             BAR;                 LGK0; MM(1, 0);
                    VMW0; BAR;                       MM(1, 1);
  RD_A(1, 0); RD_B(1, 0); BAR;                 LGK0; MM(0, 0);
  RD_B(1, 1);             BAR;                 LGK0; MM(0, 1);
  RD_A(1, 1);             BAR;                 LGK0; MM(1, 0);
                                                     MM(1, 1);

  const int mbase = m0 + wm * 128;
  const int nbase = n0 + wn * 64;

  if (nblk >= 8 && nblk < 16) {
    float w12 = (q == 3) ? 1.0f : (q == 2) ? 0.81450625f
              : (q == 1) ? 0.66342043f : 0.54036009f;   // 0.95^(12-4*q)
    w12 *= 0.05f;
#pragma unroll
    for (int mi = 0; mi < 8; ++mi) {
      const int mrow = mbase + mi * 16;
      const int bb = mrow >> 11;
      const int chh = (mrow >> 4) & (NCH - 1);
      const bool first = (chh == 0);
#pragma unroll
      for (int ni = 0; ni < 4; ++ni) {
        float v0 = acc[mi][ni][0];
        float s = ((v0 * 0.95f + acc[mi][ni][1]) * 0.95f + acc[mi][ni][2]) * 0.95f
                  + acc[mi][ni][3];
        if (first && q == 0) s += 19.0f * 0.857375f * v0;  // row0 coef -> 0.95^15
        s *= w12;
        s += __shfl_xor(s, 16);
        s += __shfl_xor(s, 32);
        if (q == 0) {
          int nloc = nbase + ni * 16 + rA - 2048;
          cpb[((size_t)bb * NCH + chh) * DH + nloc] = f2bf(s);
        }
      }
    }
  }

  // Z write: ni innermost so each (mi,rg) row's 128B line is completed by 4
  // temporally-adjacent stores (L2 merges -> clean HBM write lines).
#pragma unroll
  for (int mi = 0; mi < 8; ++mi) {
#pragma unroll
    for (int rg = 0; rg < 4; ++rg) {
      const int m = mbase + mi * 16 + q * 4 + rg;
#pragma unroll
      for (int ni = 0; ni < 4; ++ni) {
        const int n = nbase + ni * 16 + rA;
        Z[(size_t)m * NZ + n] = f2bf(acc[mi][ni][rg]);
      }
    }
  }
}

#undef BAR
#undef VMW6
#undef VMW4
#undef VMW0
#undef LGK0
#undef ST_A
#undef ST_B
#undef RD_A
#undef RD_B
#undef MM

// ---- prefix level 1: within-group (16 chunks) relative prefix + RAW group totals ----
// (zi_p2 eliminated: final_combine computes carry-into-group as
//  gc[g-1] + LAM2*gc[g-2]; LAM2^2 ~ 4e-12 terms negligible vs bf16 threshold)
__global__ __launch_bounds__(256) void zi_p1(unsigned short* __restrict__ cpb,
                                             float* __restrict__ gc) {
  int gid = blockIdx.x * 256 + threadIdx.x;   // (b, g, n): 4*8*2048 = 65536
  int n = gid & (DH - 1);
  int g = (gid >> 11) & 7;
  int b = gid >> 14;
  float run = 0.f;
#pragma unroll
  for (int j = 0; j < 16; ++j) {
    size_t idx = ((size_t)b * NCH + g * 16 + j) * DH + n;
    float c = bf2f(cpb[idx]);
    cpb[idx] = f2bf(run);
    run = c + LAM * run;
  }
  gc[((size_t)b * 8 + g) * DH + n] = run;
}

// ---- final: out = g0*Zp + g1*EMA(Zi) + g2*(Zd - Zd_prev) + cc*kvWd + bias ----
__global__ __launch_bounds__(256) void final_combine(const unsigned short* __restrict__ Z,
                                                     const float* __restrict__ rs,
                                                     const unsigned short* __restrict__ cpb,
                                                     const float* __restrict__ gc,
                                                     const float* __restrict__ kvWd,
                                                     const float* __restrict__ bias,
                                                     float* __restrict__ out) {
  int tid = threadIdx.x;
  int n = blockIdx.y * 1024 + tid * 4;  // 4 cols/thread
  int ch = blockIdx.x & (NCH - 1);      // grid (512, 2)
  int b = blockIdx.x >> 7;
  int r0 = b * TT + ch * LCH;
  const unsigned short* zb = Z + (size_t)r0 * NZ + n;
  const bool first_chunk = (ch == 0);

  int g = ch >> 4, j = ch & 15;
  float pw = 1.f;
  for (int i = 0; i < j; ++i) pw *= LAM;
  float Pv[4];
  {
    union { unsigned short u[4]; uint2 v; } c;
    c.v = *(const uint2*)&cpb[((size_t)b * NCH + ch) * DH + n];
    float gpa[4] = {0.f, 0.f, 0.f, 0.f};
    if (g >= 1) {
      float4 g1 = *(const float4*)&gc[((size_t)b * 8 + g - 1) * DH + n];
      gpa[0] = g1.x; gpa[1] = g1.y; gpa[2] = g1.z; gpa[3] = g1.w;
    }
    if (g >= 2) {
      float4 g2 = *(const float4*)&gc[((size_t)b * 8 + g - 2) * DH + n];
      gpa[0] += LAM2 * g2.x; gpa[1] += LAM2 * g2.y;
      gpa[2] += LAM2 * g2.z; gpa[3] += LAM2 * g2.w;
    }
#pragma unroll
    for (int i = 0; i < 4; ++i) Pv[i] = bf2f(c.u[i]) + pw * gpa[i];
  }
  float kv[4], bz[4];
  {
    float4 k0 = *(const float4*)&kvWd[n];
    float4 b0 = *(const float4*)&bias[n];
    kv[0]=k0.x; kv[1]=k0.y; kv[2]=k0.z; kv[3]=k0.w;
    bz[0]=b0.x; bz[1]=b0.y; bz[2]=b0.z; bz[3]=b0.w;
  }
  float zdp[4];
  if (!first_chunk) {
    union { unsigned short u[4]; uint2 v; } c;
    c.v = *(const uint2*)(zb - NZ + 2 * DH);
#pragma unroll
    for (int i = 0; i < 4; ++i) zdp[i] = bf2f(c.u[i]);
  } else {
#pragma unroll
    for (int i = 0; i < 4; ++i) zdp[i] = 0.f;
  }
  float J[4];
#pragma unroll
  for (int i = 0; i < 4; ++i) J[i] = 0.f;
  float f = 1.f;
  uint2 cp = *(const uint2*)(zb);
  uint2 ci = *(const uint2*)(zb + DH);
  uint2 cd = *(const uint2*)(zb + 2 * DH);
#pragma unroll
  for (int tau = 0; tau < LCH; ++tau) {
    uint2 np, ni, nd;
    if (tau < LCH - 1) {
      const unsigned short* zn = zb + (size_t)(tau + 1) * NZ;
      np = *(const uint2*)(zn);
      ni = *(const uint2*)(zn + DH);
      nd = *(const uint2*)(zn + 2 * DH);
    }
    float4 gg = *(const float4*)&rs[(size_t)(r0 + tau) * 4];
    union { unsigned short u[4]; uint2 v; } up, ui, ud;
    up.v = cp; ui.v = ci; ud.v = cd;
    const bool vfirst = first_chunk && (tau == 0);
    f *= 0.95f;
    float o[4];
#pragma unroll
    for (int i = 0; i < 4; ++i) {
      float xp = bf2f(up.u[i]), xi = bf2f(ui.u[i]), xd = bf2f(ud.u[i]);
      if (vfirst) J[i] = xi;
      else J[i] = 0.95f * J[i] + 0.05f * xi;
      float I = J[i] + f * Pv[i];
      float diff = vfirst ? 0.f : (xd - zdp[i]);
      o[i] = gg.x * xp + gg.y * I + gg.z * diff + gg.w * kv[i] + bz[i];
      zdp[i] = xd;
    }
    *(float4*)(out + (size_t)(r0 + tau) * DH + n) = make_float4(o[0], o[1], o[2], o[3]);
    cp = np; ci = ni; cd = nd;
  }
}

extern "C" void kernel_launch(void* const* d_in, const int* in_sizes, int n_in,
                              void* d_out, int out_size, void* d_ws, size_t ws_size,
                              hipStream_t stream) {
  const float* x        = (const float*)d_in[0];
  const float* Wp       = (const float*)d_in[1];
  const float* Wi       = (const float*)d_in[2];
  const float* Wd       = (const float*)d_in[3];
  const float* gate_w   = (const float*)d_in[4];
  const float* gate_b   = (const float*)d_in[5];
  const float* kick_vec = (const float*)d_in[6];
  const float* kick_w   = (const float*)d_in[7];
  const float* kick_b   = (const float*)d_in[8];
  const float* bias     = (const float*)d_in[9];
  float* out = (float*)d_out;

  char* ws = (char*)d_ws;
  unsigned short* Wt  = (unsigned short*)(ws + 0);           // 6144*2048*2  = 25,165,824
  unsigned short* Z   = (unsigned short*)(ws + 25165824);    // 8192*6144*2  = 100,663,296
  float* rs   = (float*)(ws + 125829120);                    // 8192*4*4     = 131,072
  float* kvWd = (float*)(ws + 125960192);                    // 2048*4       = 8,192
  unsigned short* cpb = (unsigned short*)(ws + 125968384);   // 4*128*2048*2 = 2,097,152
  float* gc   = (float*)(ws + 128065536);                    // 4*8*2048*4   = 262,144
  unsigned short* A = (unsigned short*)d_out;
  (void)ws_size; (void)in_sizes; (void)n_in; (void)out_size;

  hipMemsetAsync(kvWd, 0, DH * sizeof(float), stream);
  prep_conv<<<dim3(11264), dim3(256), 0, stream>>>(Wp, Wi, Wd, kick_vec, Wt, kvWd,
                                                   x, gate_w, gate_b, kick_w, kick_b, rs, A);
  gemm_kernel<<<dim3(768), dim3(512), 0, stream>>>(A, Wt, Z, cpb);
  zi_p1<<<dim3(256), dim3(256), 0, stream>>>(cpb, gc);
  final_combine<<<dim3(512, 2), dim3(256), 0, stream>>>(Z, rs, cpb, gc, kvWd, bias, out);
}